// Round 1
// baseline (6270.629 us; speedup 1.0000x reference)
//
#include <hip/hip_runtime.h>
#include <hip/hip_cooperative_groups.h>

namespace cg = cooperative_groups;

// ---------- problem constants ----------
#define Bz   32
#define Pz   197
#define ENCz 768
#define EMBz 512
#define HIDz 512
#define ATTz 256
#define VOCz 32000
#define Tz   40

typedef unsigned short ushort_t;
typedef __attribute__((ext_vector_type(8))) short frag_ab;     // 8 bf16 (4 VGPRs)
typedef __attribute__((ext_vector_type(4))) float frag_cd;     // 4 fp32 acc
typedef __attribute__((ext_vector_type(4))) ushort_t ushort4v; // 8B
typedef __attribute__((ext_vector_type(8))) ushort_t ushort8v; // 16B

#define MFMA16(a, b, c) __builtin_amdgcn_mfma_f32_16x16x32_bf16((a), (b), (c), 0, 0, 0)

__device__ __forceinline__ float b2f(ushort_t u) {
    return __uint_as_float(((unsigned)u) << 16);
}
__device__ __forceinline__ ushort_t f2bf(float f) {
    unsigned u = __float_as_uint(f);
    unsigned r = (u + 0x7fffu + ((u >> 16) & 1u)) >> 16;
    return (ushort_t)r;
}
__device__ __forceinline__ float sigf(float x) { return 1.f / (1.f + __expf(-x)); }
__device__ __forceinline__ float tanhfast(float x) { return 1.f - 2.f / (__expf(2.f * x) + 1.f); }

// ---------- fp32 -> bf16 bulk convert (8 elems/thread) ----------
__global__ __launch_bounds__(256) void k_conv(const float* __restrict__ in, ushort_t* __restrict__ out) {
    size_t base = ((size_t)blockIdx.x * 256 + threadIdx.x) * 8;
    const float4* src = (const float4*)(in + base);
    float4 a = src[0], b = src[1];
    ushort8v v;
    v[0] = f2bf(a.x); v[1] = f2bf(a.y); v[2] = f2bf(a.z); v[3] = f2bf(a.w);
    v[4] = f2bf(b.x); v[5] = f2bf(b.y); v[6] = f2bf(b.z); v[7] = f2bf(b.w);
    *(ushort8v*)(out + base) = v;
}

// ---------- mean over P ----------
__global__ __launch_bounds__(256) void k_mean(const float* __restrict__ enc, float* __restrict__ meanE) {
    int e = blockIdx.x * 256 + threadIdx.x;      // 32*768 = 24576
    int b = e / ENCz, d = e % ENCz;
    const float* p = enc + (size_t)b * Pz * ENCz + d;
    float s = 0.f;
    for (int i = 0; i < Pz; ++i) s += p[i * ENCz];
    meanE[e] = s * (1.f / (float)Pz);
}

// ---------- h0/c0 init (h0 bf16 lands in Abuf0 cols 768..1279) ----------
__global__ __launch_bounds__(256) void k_h0c0(const float* __restrict__ meanE,
                                              const float* __restrict__ W_inh, const float* __restrict__ b_inh,
                                              const float* __restrict__ W_inc, const float* __restrict__ b_inc,
                                              float* __restrict__ h_cur, float* __restrict__ c_cur,
                                              ushort_t* __restrict__ Abuf) {
    __shared__ float msh[ENCz];
    int bid = blockIdx.x, tid = threadIdx.x;
    int b = bid >> 2, seg = bid & 3;             // seg0/1: h halves, seg2/3: c halves
    for (int i = tid; i < ENCz; i += 256) msh[i] = meanE[b * ENCz + i];
    __syncthreads();
    int col = (seg & 1) * 256 + tid;
    bool isc = (seg >> 1) != 0;
    const float* W = isc ? W_inc : W_inh;
    const float* bb = isc ? b_inc : b_inh;
    float a0 = 0.f, a1 = 0.f, a2 = 0.f, a3 = 0.f;
    for (int k = 0; k < ENCz; k += 4) {
        a0 += msh[k + 0] * W[(k + 0) * HIDz + col];
        a1 += msh[k + 1] * W[(k + 1) * HIDz + col];
        a2 += msh[k + 2] * W[(k + 2) * HIDz + col];
        a3 += msh[k + 3] * W[(k + 3) * HIDz + col];
    }
    float acc = a0 + a1 + a2 + a3 + bb[col];
    if (isc) c_cur[b * HIDz + col] = acc;
    else { h_cur[b * HIDz + col] = acc; Abuf[b * 1280 + 768 + col] = f2bf(acc); }
}

// ---------- embedding gather+convert ----------
__global__ __launch_bounds__(128) void k_gather(const int* __restrict__ captions, const float* __restrict__ emb,
                                                ushort_t* __restrict__ Xemb) {
    int row = blockIdx.x;                        // 0..1279 = t*32+b
    int t = row >> 5, b = row & 31;
    int cap = captions[b * 41 + t];
    float4 f = *(const float4*)(emb + (size_t)cap * EMBz + threadIdx.x * 4);
    ushort4v v; v[0] = f2bf(f.x); v[1] = f2bf(f.y); v[2] = f2bf(f.z); v[3] = f2bf(f.w);
    *(ushort4v*)(Xemb + (size_t)row * EMBz + threadIdx.x * 4) = v;
}

// ---------- fp32-in / bf16-out transpose ----------
__global__ __launch_bounds__(256) void k_transpose(const float* __restrict__ in, int R, int C,
                                                   ushort_t* __restrict__ out, int ldo, int koff) {
    __shared__ ushort_t tile[32][33];
    int c0 = blockIdx.x * 32, r0 = blockIdx.y * 32;
    int tx = threadIdx.x & 31, ty = threadIdx.x >> 5;    // ty 0..7
#pragma unroll
    for (int i = 0; i < 4; ++i) {
        int r = r0 + ty + i * 8;
        tile[ty + i * 8][tx] = f2bf(in[(size_t)r * C + c0 + tx]);
    }
    __syncthreads();
#pragma unroll
    for (int i = 0; i < 4; ++i) {
        int c = c0 + ty + i * 8;
        out[(size_t)c * ldo + koff + r0 + tx] = tile[tx][ty + i * 8];
    }
}

// ---------- MFMA GEMM ----------
// MODE 0: fp32 out (ldo), bias1+bias2
// MODE 2: fp32 out permuted for final preds (row m=t*32+b -> out[b][t][n]), XCD-swizzled grid
// MODE 3: bf16 out transposed att1T: row m=b*197+p, col n -> out[(b*256+n)*197+p]
template <int MODE>
__global__ __launch_bounds__(256) void k_gemm(const ushort_t* __restrict__ A, int lda, int M,
                                              const ushort_t* __restrict__ BT, int K,
                                              const float* __restrict__ B1, const float* __restrict__ B2,
                                              void* __restrict__ out, int ldo) {
    __shared__ __align__(16) ushort_t As[128 * 64];
    __shared__ __align__(16) ushort_t Bs[128 * 64];
    const int tid = threadIdx.x;
    const int lane = tid & 63, w = tid >> 6;
    const int wm = w >> 1, wn = w & 1;
    int n0, m0;
    if (MODE == 2) {
        // bijective XCD swizzle (n-major chunks): all M-blocks of an n-slice land on one XCD
        const int total = gridDim.x * gridDim.y;
        const int lin = blockIdx.y * gridDim.x + blockIdx.x;
        const int q = total >> 3, r = total - (q << 3);
        const int xcd = lin & 7, slot = lin >> 3;
        const int L = (xcd < r) ? xcd * (q + 1) + slot : r * (q + 1) + (xcd - r) * q + slot;
        const int nIdx = L / (int)gridDim.y;
        n0 = nIdx * 128; m0 = (L - nIdx * (int)gridDim.y) * 128;
    } else {
        n0 = blockIdx.x * 128; m0 = blockIdx.y * 128;
    }
    const int quad = lane >> 4, c16 = lane & 15;

    frag_cd acc[4][4];
#pragma unroll
    for (int i = 0; i < 4; ++i)
#pragma unroll
        for (int j = 0; j < 4; ++j) acc[i][j] = (frag_cd){0.f, 0.f, 0.f, 0.f};

    for (int k0 = 0; k0 < K; k0 += 64) {
#pragma unroll
        for (int it = 0; it < 4; ++it) {
            int c = tid + it * 256;              // chunk 0..1023
            int row = c >> 3, col8 = (c & 7) * 8;
            int gr = m0 + row; gr = gr < M ? gr : M - 1;
            *(frag_ab*)&As[row * 64 + col8] = *(const frag_ab*)&A[(size_t)gr * lda + k0 + col8];
            *(frag_ab*)&Bs[row * 64 + col8] = *(const frag_ab*)&BT[(size_t)(n0 + row) * K + k0 + col8];
        }
        __syncthreads();
#pragma unroll
        for (int kk = 0; kk < 64; kk += 32) {
            int kcol = kk + quad * 8;
            frag_ab af[4], bf[4];
#pragma unroll
            for (int i = 0; i < 4; ++i) af[i] = *(const frag_ab*)&As[(wm * 64 + i * 16 + c16) * 64 + kcol];
#pragma unroll
            for (int j = 0; j < 4; ++j) bf[j] = *(const frag_ab*)&Bs[(wn * 64 + j * 16 + c16) * 64 + kcol];
#pragma unroll
            for (int i = 0; i < 4; ++i)
#pragma unroll
                for (int j = 0; j < 4; ++j) acc[i][j] = MFMA16(af[i], bf[j], acc[i][j]);
        }
        __syncthreads();
    }

#pragma unroll
    for (int i = 0; i < 4; ++i) {
#pragma unroll
        for (int j = 0; j < 4; ++j) {
            int n = n0 + wn * 64 + j * 16 + c16;
            float bias = B1[n];
            if (B2 != nullptr) bias += B2[n];
#pragma unroll
            for (int r = 0; r < 4; ++r) {
                int m = m0 + wm * 64 + i * 16 + quad * 4 + r;
                float v = acc[i][j][r] + bias;
                if (MODE == 0) {
                    if (m < M) ((float*)out)[(size_t)m * ldo + n] = v;
                } else if (MODE == 2) {
                    int b = m & 31, t = m >> 5;
                    ((float*)out)[(size_t)b * (Tz * VOCz) + (size_t)t * VOCz + n] = v;
                } else {  // MODE 3
                    if (m < M) {
                        unsigned mm = (unsigned)m;
                        unsigned bb = mm / 197u;
                        unsigned pp = mm - bb * 197u;
                        ((ushort_t*)out)[((size_t)(bb * 256u + (unsigned)n)) * 197 + pp] = f2bf(v);
                    }
                }
            }
        }
    }
}

// ---------- persistent cooperative recurrence kernel ----------
// 256 blocks x 256 threads, 3 grid syncs per step.
// P1: blocks 0..31  -> e[b][p] (p-parallel, att1T layout); blocks 32..127 -> gate[b][col]
// P2: all 256 blocks (b, enc-chunk of 96) -> softmax + awe + gawe bf16 into Abuf[t&1]
// P3: all 256 blocks (jq=g>>1 -> 4 hid cols, mh=g&1 -> 16 batch rows): MFMA gates GEMM
//     with per-block Wg columns resident in LDS for all 40 steps; LSTM with c in registers.
__global__ __launch_bounds__(256, 1) void k_recur(
    const float* __restrict__ enc, const ushort_t* __restrict__ att1T,
    const float* __restrict__ W_da, const float* __restrict__ b_da,
    const float* __restrict__ w_fa, const float* __restrict__ b_fa,
    const float* __restrict__ W_fb, const float* __restrict__ b_fb,
    const ushort_t* __restrict__ WgT, const float* __restrict__ Xih,
    const float* __restrict__ c0, float* __restrict__ h_cur,
    ushort_t* __restrict__ Abuf, float* __restrict__ e_buf,
    float* __restrict__ gate_buf, ushort_t* __restrict__ Hall)
{
    cg::grid_group grid = cg::this_grid();
    __shared__ __align__(16) ushort_t Wl[16][1288];   // 16 Wg cols, padded rows (41.2 KB, persistent)
    __shared__ float sh[1024];                        // per-phase scratch
    __shared__ float gsh[4][16][16];                  // P3 K-split partials
    __shared__ float gsh2[16][16];

    const int g = (int)blockIdx.x;
    const int tid = (int)threadIdx.x;
    const int lane = tid & 63, wv = tid >> 6;
    const int quad = lane >> 4, c16 = lane & 15;
    const int jq = g >> 1, mh = g & 1, j0 = jq << 2;

    // one-time: stage this block's 16 Wg columns (col r -> (r>>2)*512 + j0 + (r&3))
    {
        int r = tid >> 4, ch = tid & 15;
        int coln = ((r >> 2) << 9) + j0 + (r & 3);
        const ushort_t* src = WgT + (size_t)coln * 1280 + ch * 80;
        ushort_t* dst = &Wl[r][ch * 80];
#pragma unroll
        for (int i = 0; i < 10; ++i)
            *(ushort8v*)(dst + i * 8) = *(const ushort8v*)(src + i * 8);
    }
    // one-time: c into registers (block-private (b,j) pairs for all 40 steps)
    float creg = 0.f;
    if (tid < 64) creg = c0[(mh * 16 + (tid >> 2)) * HIDz + j0 + (tid & 3)];

    for (int t = 0; t < Tz; ++t) {
        ushort_t* Ab_r = Abuf + (size_t)(t & 1) * 40960;          // read by P3(t), gawe by P2(t)
        ushort_t* Ab_w = Abuf + (size_t)((t + 1) & 1) * 40960;    // h written by P3(t)

        // ================= P1 =================
        if (g < 32) {
            const int b = g;
            sh[tid] = h_cur[b * HIDz + tid];
            sh[256 + tid] = h_cur[b * HIDz + 256 + tid];
            sh[768 + tid] = w_fa[tid];
            __syncthreads();
            float a0 = 0.f, a1 = 0.f, a2 = 0.f, a3 = 0.f;
            const float* Wd = W_da + tid;
            for (int k = 0; k < HIDz; k += 4) {
                a0 += sh[k + 0] * Wd[(k + 0) * ATTz];
                a1 += sh[k + 1] * Wd[(k + 1) * ATTz];
                a2 += sh[k + 2] * Wd[(k + 2) * ATTz];
                a3 += sh[k + 3] * Wd[(k + 3) * ATTz];
            }
            sh[512 + tid] = a0 + a1 + a2 + a3 + b_da[tid];
            __syncthreads();
            if (tid < Pz) {
                const ushort_t* colp = att1T + ((size_t)b << 8) * 197 + tid;
                float s = 0.f;
#pragma unroll 4
                for (int j = 0; j < ATTz; ++j)
                    s += fmaxf(b2f(colp[(size_t)j * 197]) + sh[512 + j], 0.f) * sh[768 + j];
                e_buf[b * Pz + tid] = s + b_fa[0];
            }
        } else if (g < 128) {
            const int idx = g - 32;
            const int b = idx / 3, seg = idx - b * 3;
            sh[tid] = h_cur[b * HIDz + tid];
            sh[256 + tid] = h_cur[b * HIDz + 256 + tid];
            __syncthreads();
            const int col = seg * 256 + tid;
            float a0 = 0.f, a1 = 0.f, a2 = 0.f, a3 = 0.f;
            const float* Wf = W_fb + col;
            for (int k = 0; k < HIDz; k += 4) {
                a0 += sh[k + 0] * Wf[(k + 0) * ENCz];
                a1 += sh[k + 1] * Wf[(k + 1) * ENCz];
                a2 += sh[k + 2] * Wf[(k + 2) * ENCz];
                a3 += sh[k + 3] * Wf[(k + 3) * ENCz];
            }
            gate_buf[b * ENCz + col] = sigf(a0 + a1 + a2 + a3 + b_fb[col]);
        }
        grid.sync();

        // ================= P2 =================
        {
            const int b = g >> 3, d0 = (g & 7) * 96;
            float ev = (tid < Pz) ? e_buf[b * Pz + tid] : -3.0e38f;
            float mv = ev;
            for (int o = 32; o; o >>= 1) mv = fmaxf(mv, __shfl_down(mv, o, 64));
            if (lane == 0) sh[200 + wv] = mv;
            __syncthreads();
            const float mx = fmaxf(fmaxf(sh[200], sh[201]), fmaxf(sh[202], sh[203]));
            float ex = (tid < Pz) ? __expf(ev - mx) : 0.f;
            float sv = ex;
            for (int o = 32; o; o >>= 1) sv += __shfl_down(sv, o, 64);
            if (lane == 0) sh[204 + wv] = sv;
            if (tid < Pz) sh[256 + tid] = ex;
            __syncthreads();
            const float inv = 1.f / (sh[204] + sh[205] + sh[206] + sh[207]);
            if (tid < 96) {
                const int d = d0 + tid;
                const float* ep = enc + (size_t)b * Pz * ENCz + d;
                float ac = 0.f;
#pragma unroll 4
                for (int p = 0; p < Pz; ++p) ac += sh[256 + p] * ep[(size_t)p * ENCz];
                ac *= inv * gate_buf[b * ENCz + d];
                Ab_r[b * 1280 + d] = f2bf(ac);
            }
        }
        grid.sync();

        // ================= P3 =================
        {
            frag_cd pacc = (frag_cd){0.f, 0.f, 0.f, 0.f};
            const ushort_t* Ar = Ab_r + (size_t)(mh * 16 + c16) * 1280 + wv * 320 + quad * 8;
            const ushort_t* Wr = &Wl[c16][wv * 320 + quad * 8];
#pragma unroll
            for (int ks = 0; ks < 10; ++ks)
                pacc = MFMA16(*(const frag_ab*)(Ar + ks * 32), *(const frag_ab*)(Wr + ks * 32), pacc);
#pragma unroll
            for (int r = 0; r < 4; ++r) gsh[wv][quad * 4 + r][c16] = pacc[r];
            __syncthreads();
            {
                const int row = tid >> 4, col = tid & 15;
                float s = gsh[0][row][col] + gsh[1][row][col] + gsh[2][row][col] + gsh[3][row][col];
                s += Xih[(size_t)t * 65536 + (mh * 16 + row) * 2048 + ((col >> 2) << 9) + j0 + (col & 3)];
                gsh2[row][col] = s;
            }
            __syncthreads();
            if (tid < 64) {
                const int bl = tid >> 2, jj = tid & 3;
                const int b = mh * 16 + bl, j = j0 + jj;
                const float iv = gsh2[bl][jj], fv = gsh2[bl][4 + jj];
                const float gv = gsh2[bl][8 + jj], ov = gsh2[bl][12 + jj];
                const float cn = sigf(fv) * creg + sigf(iv) * tanhfast(gv);
                creg = cn;
                const float hn = sigf(ov) * tanhfast(cn);
                h_cur[b * HIDz + j] = hn;
                const ushort_t hb = f2bf(hn);
                Ab_w[b * 1280 + 768 + j] = hb;
                Hall[((size_t)t * 32 + b) * HIDz + j] = hb;
            }
        }
        if (t < Tz - 1) grid.sync();
    }
}

// ---------- launcher ----------
extern "C" void kernel_launch(void* const* d_in, const int* in_sizes, int n_in,
                              void* d_out, int out_size, void* d_ws, size_t ws_size,
                              hipStream_t stream) {
    const float* enc   = (const float*)d_in[0];
    const int*   caps  = (const int*)d_in[1];
    const float* emb   = (const float*)d_in[2];
    const float* W_ea  = (const float*)d_in[3];
    const float* b_ea  = (const float*)d_in[4];
    const float* W_da  = (const float*)d_in[5];
    const float* b_da  = (const float*)d_in[6];
    const float* w_fa  = (const float*)d_in[7];
    const float* b_fa  = (const float*)d_in[8];
    const float* W_inh = (const float*)d_in[9];
    const float* b_inh = (const float*)d_in[10];
    const float* W_inc = (const float*)d_in[11];
    const float* b_inc = (const float*)d_in[12];
    const float* W_fb  = (const float*)d_in[13];
    const float* b_fb  = (const float*)d_in[14];
    const float* W_ih  = (const float*)d_in[15];
    const float* b_ih  = (const float*)d_in[16];
    const float* W_hh  = (const float*)d_in[17];
    const float* b_hh  = (const float*)d_in[18];
    const float* W_out = (const float*)d_in[19];
    const float* b_out = (const float*)d_in[20];

    char* ws = (char*)d_ws;
    ushort_t* att1T   = (ushort_t*)(ws + 0);             // 32*256*197 bf16 = 3,227,648
    ushort_t* Xemb    = (ushort_t*)(ws + 3227648);       // 1280x512 bf16
    ushort_t* encB    = (ushort_t*)(ws + 4538368);       // 6304x768 bf16
    float*    Xih     = (float*)(ws + 14221312);         // 40x32x2048 fp32
    float*    meanE   = (float*)(ws + 24707072);         // 32x768 (reused as e_buf)
    float*    h_cur   = (float*)(ws + 24805376);         // 32x512
    float*    c_cur   = (float*)(ws + 24870912);         // 32x512
    ushort_t* Abuf    = (ushort_t*)(ws + 24936448);      // 2 x 32x1280 bf16 (double-buffered)
    float*    gate_buf= (float*)(ws + 25100288);         // 32x768
    ushort_t* Hall    = (ushort_t*)(ws + 25198592);      // 1280x512 bf16
    ushort_t* WgT     = (ushort_t*)(ws + 26509312);      // 2048x1280 bf16
    ushort_t* W_eaT   = (ushort_t*)(ws + 31752192);      // 256x768 bf16
    ushort_t* W_ihxT  = (ushort_t*)(ws + 32145408);      // 2048x512 bf16
    ushort_t* W_outT  = (ushort_t*)(ws + 34242560);      // 32000x512 bf16
    float*    e_buf   = meanE;                           // 32x197 fp32 (meanE dead after k_h0c0)

    // precompute (order-independent, single stream)
    k_conv<<<2364, 256, 0, stream>>>(enc, encB);         // 32*197*768 = 2364*2048
    k_mean<<<96, 256, 0, stream>>>(enc, meanE);
    k_h0c0<<<128, 256, 0, stream>>>(meanE, W_inh, b_inh, W_inc, b_inc, h_cur, c_cur, Abuf);
    k_gather<<<1280, 128, 0, stream>>>(caps, emb, Xemb);
    k_transpose<<<dim3(8, 24), 256, 0, stream>>>(W_ea, 768, 256, W_eaT, 768, 0);
    k_transpose<<<dim3(64, 16), 256, 0, stream>>>(W_ih, 512, 2048, W_ihxT, 512, 0);
    k_transpose<<<dim3(64, 24), 256, 0, stream>>>(W_ih + 512 * 2048, 768, 2048, WgT, 1280, 0);
    k_transpose<<<dim3(64, 16), 256, 0, stream>>>(W_hh, 512, 2048, WgT, 1280, 768);
    k_transpose<<<dim3(1000, 16), 256, 0, stream>>>(W_out, 512, 32000, W_outT, 512, 0);

    // att1T[(b*256+j)*197+p] = bf16(enc @ W_ea + b_ea)
    k_gemm<3><<<dim3(2, 50), 256, 0, stream>>>(encB, 768, 6304, W_eaT, 768, b_ea, nullptr, att1T, 0);
    // Xih = Xemb @ W_ih[:512] + b_ih + b_hh  (fp32 out)
    k_gemm<0><<<dim3(16, 10), 256, 0, stream>>>(Xemb, 512, 1280, W_ihxT, 512, b_ih, b_hh, Xih, 2048);

    // full 40-step recurrence: one cooperative kernel, 3 grid syncs per step
    {
        void* kargs[16] = {
            (void*)&enc, (void*)&att1T, (void*)&W_da, (void*)&b_da, (void*)&w_fa, (void*)&b_fa,
            (void*)&W_fb, (void*)&b_fb, (void*)&WgT, (void*)&Xih, (void*)&c_cur, (void*)&h_cur,
            (void*)&Abuf, (void*)&e_buf, (void*)&gate_buf, (void*)&Hall
        };
        hipLaunchCooperativeKernel((void*)k_recur, dim3(256), dim3(256), kargs, 0, stream);
    }

    // preds = Hall @ W_out + b_out -> d_out (B,T,V) fp32
    k_gemm<2><<<dim3(250, 10), 256, 0, stream>>>(Hall, 512, 1280, W_outT, 512, b_out, nullptr, d_out, VOCz);
}

// Round 2
// 2610.706 us; speedup vs baseline: 2.4019x; 2.4019x over previous
//
#include <hip/hip_runtime.h>

// ---------- problem constants ----------
#define Bz   32
#define Pz   197
#define ENCz 768
#define EMBz 512
#define HIDz 512
#define ATTz 256
#define VOCz 32000
#define Tz   40

typedef unsigned short ushort_t;
typedef __attribute__((ext_vector_type(8))) short frag_ab;     // 8 bf16 (4 VGPRs)
typedef __attribute__((ext_vector_type(4))) float frag_cd;     // 4 fp32 acc
typedef __attribute__((ext_vector_type(4))) ushort_t ushort4v; // 8B
typedef __attribute__((ext_vector_type(8))) ushort_t ushort8v; // 16B

#define MFMA16(a, b, c) __builtin_amdgcn_mfma_f32_16x16x32_bf16((a), (b), (c), 0, 0, 0)

__device__ __forceinline__ float b2f(ushort_t u) {
    return __uint_as_float(((unsigned)u) << 16);
}
__device__ __forceinline__ ushort_t f2bf(float f) {
    unsigned u = __float_as_uint(f);
    unsigned r = (u + 0x7fffu + ((u >> 16) & 1u)) >> 16;
    return (ushort_t)r;
}
__device__ __forceinline__ float sigf(float x) { return 1.f / (1.f + __expf(-x)); }
__device__ __forceinline__ float tanhfast(float x) { return 1.f - 2.f / (__expf(2.f * x) + 1.f); }

// ---------- fast grid barrier (monotonic counter, device-scope) ----------
__device__ __forceinline__ void gbar(unsigned* cnt, unsigned target) {
    __syncthreads();
    if (threadIdx.x == 0) {
        __builtin_amdgcn_fence(__ATOMIC_RELEASE, "agent");
        __hip_atomic_fetch_add(cnt, 1u, __ATOMIC_RELAXED, __HIP_MEMORY_SCOPE_AGENT);
        while (__hip_atomic_load(cnt, __ATOMIC_RELAXED, __HIP_MEMORY_SCOPE_AGENT) < target) {
            __builtin_amdgcn_s_sleep(1);
        }
        __builtin_amdgcn_fence(__ATOMIC_ACQUIRE, "agent");
    }
    __syncthreads();
}

__global__ void k_binit(unsigned* c) { if (threadIdx.x == 0) *c = 0u; }

// ---------- fp32 -> bf16 bulk convert (8 elems/thread) ----------
__global__ __launch_bounds__(256) void k_conv(const float* __restrict__ in, ushort_t* __restrict__ out) {
    size_t base = ((size_t)blockIdx.x * 256 + threadIdx.x) * 8;
    const float4* src = (const float4*)(in + base);
    float4 a = src[0], b = src[1];
    ushort8v v;
    v[0] = f2bf(a.x); v[1] = f2bf(a.y); v[2] = f2bf(a.z); v[3] = f2bf(a.w);
    v[4] = f2bf(b.x); v[5] = f2bf(b.y); v[6] = f2bf(b.z); v[7] = f2bf(b.w);
    *(ushort8v*)(out + base) = v;
}

// ---------- mean over P ----------
__global__ __launch_bounds__(256) void k_mean(const float* __restrict__ enc, float* __restrict__ meanE) {
    int e = blockIdx.x * 256 + threadIdx.x;      // 32*768 = 24576
    int b = e / ENCz, d = e % ENCz;
    const float* p = enc + (size_t)b * Pz * ENCz + d;
    float s = 0.f;
    for (int i = 0; i < Pz; ++i) s += p[i * ENCz];
    meanE[e] = s * (1.f / (float)Pz);
}

// ---------- h0/c0 init (h0 bf16 lands in Abuf0 cols 768..1279) ----------
__global__ __launch_bounds__(256) void k_h0c0(const float* __restrict__ meanE,
                                              const float* __restrict__ W_inh, const float* __restrict__ b_inh,
                                              const float* __restrict__ W_inc, const float* __restrict__ b_inc,
                                              float* __restrict__ c_cur, ushort_t* __restrict__ Abuf) {
    __shared__ float msh[ENCz];
    int bid = blockIdx.x, tid = threadIdx.x;
    int b = bid >> 2, seg = bid & 3;             // seg0/1: h halves, seg2/3: c halves
    for (int i = tid; i < ENCz; i += 256) msh[i] = meanE[b * ENCz + i];
    __syncthreads();
    int col = (seg & 1) * 256 + tid;
    bool isc = (seg >> 1) != 0;
    const float* W = isc ? W_inc : W_inh;
    const float* bb = isc ? b_inc : b_inh;
    float a0 = 0.f, a1 = 0.f, a2 = 0.f, a3 = 0.f;
    for (int k = 0; k < ENCz; k += 4) {
        a0 += msh[k + 0] * W[(k + 0) * HIDz + col];
        a1 += msh[k + 1] * W[(k + 1) * HIDz + col];
        a2 += msh[k + 2] * W[(k + 2) * HIDz + col];
        a3 += msh[k + 3] * W[(k + 3) * HIDz + col];
    }
    float acc = a0 + a1 + a2 + a3 + bb[col];
    if (isc) c_cur[b * HIDz + col] = acc;
    else Abuf[b * 1280 + 768 + col] = f2bf(acc);
}

// ---------- embedding gather+convert ----------
__global__ __launch_bounds__(128) void k_gather(const int* __restrict__ captions, const float* __restrict__ emb,
                                                ushort_t* __restrict__ Xemb) {
    int row = blockIdx.x;                        // 0..1279 = t*32+b
    int t = row >> 5, b = row & 31;
    int cap = captions[b * 41 + t];
    float4 f = *(const float4*)(emb + (size_t)cap * EMBz + threadIdx.x * 4);
    ushort4v v; v[0] = f2bf(f.x); v[1] = f2bf(f.y); v[2] = f2bf(f.z); v[3] = f2bf(f.w);
    *(ushort4v*)(Xemb + (size_t)row * EMBz + threadIdx.x * 4) = v;
}

// ---------- fp32-in / bf16-out transpose ----------
__global__ __launch_bounds__(256) void k_transpose(const float* __restrict__ in, int R, int C,
                                                   ushort_t* __restrict__ out, int ldo, int koff) {
    __shared__ ushort_t tile[32][33];
    int c0 = blockIdx.x * 32, r0 = blockIdx.y * 32;
    int tx = threadIdx.x & 31, ty = threadIdx.x >> 5;    // ty 0..7
#pragma unroll
    for (int i = 0; i < 4; ++i) {
        int r = r0 + ty + i * 8;
        tile[ty + i * 8][tx] = f2bf(in[(size_t)r * C + c0 + tx]);
    }
    __syncthreads();
#pragma unroll
    for (int i = 0; i < 4; ++i) {
        int c = c0 + ty + i * 8;
        out[(size_t)c * ldo + koff + r0 + tx] = tile[tx][ty + i * 8];
    }
}

// ---------- enc transpose fp32: encT[b][d][p] (p padded to 200, pad=0) ----------
__global__ __launch_bounds__(256) void k_encT(const float* __restrict__ enc, float* __restrict__ encT) {
    __shared__ float tile[32][33];
    int b = blockIdx.z;
    int d0 = blockIdx.x * 32, p0 = blockIdx.y * 32;
    int tx = threadIdx.x & 31, ty = threadIdx.x >> 5;
#pragma unroll
    for (int i = 0; i < 4; ++i) {
        int p = p0 + ty + i * 8;
        tile[ty + i * 8][tx] = (p < Pz) ? enc[((size_t)b * Pz + p) * ENCz + d0 + tx] : 0.f;
    }
    __syncthreads();
#pragma unroll
    for (int i = 0; i < 4; ++i) {
        int d = d0 + ty + i * 8, p = p0 + tx;
        if (p < 200) encT[((size_t)b * ENCz + d) * 200 + p] = tile[tx][ty + i * 8];
    }
}

// ---------- MFMA GEMM ----------
// MODE 0: fp32 out (ldo), bias1+bias2;  MODE 1: bf16 out (ldo), bias1, row-guard
// MODE 2: fp32 out permuted for final preds (row m=t*32+b -> out[b][t][n]), XCD-swizzled grid
template <int MODE>
__global__ __launch_bounds__(256) void k_gemm(const ushort_t* __restrict__ A, int lda, int M,
                                              const ushort_t* __restrict__ BT, int K,
                                              const float* __restrict__ B1, const float* __restrict__ B2,
                                              void* __restrict__ out, int ldo) {
    __shared__ __align__(16) ushort_t As[128 * 64];
    __shared__ __align__(16) ushort_t Bs[128 * 64];
    const int tid = threadIdx.x;
    const int lane = tid & 63, w = tid >> 6;
    const int wm = w >> 1, wn = w & 1;
    int n0, m0;
    if (MODE == 2) {
        const int total = gridDim.x * gridDim.y;
        const int lin = blockIdx.y * gridDim.x + blockIdx.x;
        const int q = total >> 3, r = total - (q << 3);
        const int xcd = lin & 7, slot = lin >> 3;
        const int L = (xcd < r) ? xcd * (q + 1) + slot : r * (q + 1) + (xcd - r) * q + slot;
        const int nIdx = L / (int)gridDim.y;
        n0 = nIdx * 128; m0 = (L - nIdx * (int)gridDim.y) * 128;
    } else {
        n0 = blockIdx.x * 128; m0 = blockIdx.y * 128;
    }
    const int quad = lane >> 4, c16 = lane & 15;

    frag_cd acc[4][4];
#pragma unroll
    for (int i = 0; i < 4; ++i)
#pragma unroll
        for (int j = 0; j < 4; ++j) acc[i][j] = (frag_cd){0.f, 0.f, 0.f, 0.f};

    for (int k0 = 0; k0 < K; k0 += 64) {
#pragma unroll
        for (int it = 0; it < 4; ++it) {
            int c = tid + it * 256;              // chunk 0..1023
            int row = c >> 3, col8 = (c & 7) * 8;
            int gr = m0 + row; gr = gr < M ? gr : M - 1;
            *(frag_ab*)&As[row * 64 + col8] = *(const frag_ab*)&A[(size_t)gr * lda + k0 + col8];
            *(frag_ab*)&Bs[row * 64 + col8] = *(const frag_ab*)&BT[(size_t)(n0 + row) * K + k0 + col8];
        }
        __syncthreads();
#pragma unroll
        for (int kk = 0; kk < 64; kk += 32) {
            int kcol = kk + quad * 8;
            frag_ab af[4], bf[4];
#pragma unroll
            for (int i = 0; i < 4; ++i) af[i] = *(const frag_ab*)&As[(wm * 64 + i * 16 + c16) * 64 + kcol];
#pragma unroll
            for (int j = 0; j < 4; ++j) bf[j] = *(const frag_ab*)&Bs[(wn * 64 + j * 16 + c16) * 64 + kcol];
#pragma unroll
            for (int i = 0; i < 4; ++i)
#pragma unroll
                for (int j = 0; j < 4; ++j) acc[i][j] = MFMA16(af[i], bf[j], acc[i][j]);
        }
        __syncthreads();
    }

#pragma unroll
    for (int i = 0; i < 4; ++i) {
#pragma unroll
        for (int j = 0; j < 4; ++j) {
            int n = n0 + wn * 64 + j * 16 + c16;
            float bias = B1[n];
            if (B2 != nullptr) bias += B2[n];
#pragma unroll
            for (int r = 0; r < 4; ++r) {
                int m = m0 + wm * 64 + i * 16 + quad * 4 + r;
                float v = acc[i][j][r] + bias;
                if (MODE == 0) {
                    if (m < M) ((float*)out)[(size_t)m * ldo + n] = v;
                } else if (MODE == 1) {
                    if (m < M) ((ushort_t*)out)[(size_t)m * ldo + n] = f2bf(v);
                } else {
                    int b = m & 31, t = m >> 5;
                    ((float*)out)[(size_t)b * (Tz * VOCz) + (size_t)t * VOCz + n] = v;
                }
            }
        }
    }
}

// ---------- persistent recurrence kernel, custom barriers ----------
// S1 (64 blocks): pre = h_bf @ W_pre (att2 | gate) via MFMA, 16 cols/block, 4-wave K-split.
// S2 (256 blocks, b = g>>3, dc = g&7): e (contig att1 rows) + softmax + awe (contig encT) + gawe.
// S3 (256 blocks): gates GEMM (Wl LDS-resident) + LSTM (c in regs) -> h(t+1) bf16.
__global__ __launch_bounds__(256, 1) void k_recur(
    const ushort_t* __restrict__ att1, const float* __restrict__ encT,
    const ushort_t* __restrict__ W_preT, const float* __restrict__ b_da,
    const float* __restrict__ b_fb, const float* __restrict__ w_fa,
    const float* __restrict__ b_fa, const ushort_t* __restrict__ WgT,
    const float* __restrict__ Xih, const float* __restrict__ c0,
    ushort_t* __restrict__ Abuf, float* __restrict__ att2_buf,
    float* __restrict__ gate_buf, ushort_t* __restrict__ Hall,
    unsigned* __restrict__ barcnt)
{
    __shared__ __align__(16) ushort_t Wl[16][1288];   // 16 Wg cols, persistent (41.2 KB)
    __shared__ __align__(16) float scratch[2048];     // 8 KB phase scratch

    const int g = (int)blockIdx.x;
    const int tid = (int)threadIdx.x;
    const int lane = tid & 63, wv = tid >> 6;
    const int quad = lane >> 4, c16 = lane & 15;
    const int jq = g >> 1, mh = g & 1, j0 = jq << 2;

    // one-time: stage this block's 16 Wg columns (col r -> (r>>2)*512 + j0 + (r&3))
    {
        int r = tid >> 4, ch = tid & 15;
        int coln = ((r >> 2) << 9) + j0 + (r & 3);
        const ushort_t* src = WgT + (size_t)coln * 1280 + ch * 80;
        ushort_t* dst = &Wl[r][ch * 80];
#pragma unroll
        for (int i = 0; i < 10; ++i)
            *(ushort8v*)(dst + i * 8) = *(const ushort8v*)(src + i * 8);
    }
    float creg = 0.f;
    if (tid < 64) creg = c0[(mh * 16 + (tid >> 2)) * HIDz + j0 + (tid & 3)];

    unsigned bt = 0;
    for (int t = 0; t < Tz; ++t) {
        ushort_t* Ab_r = Abuf + (size_t)(t & 1) * 40960;
        ushort_t* Ab_w = Abuf + (size_t)((t + 1) & 1) * 40960;

        // ============ S1: pre-GEMM (att2 + gate) ============
        if (g < 64) {
            const int n0 = g << 4;
            frag_cd a0 = (frag_cd){0.f, 0.f, 0.f, 0.f};
            frag_cd a1 = (frag_cd){0.f, 0.f, 0.f, 0.f};
            const ushort_t* Wp = W_preT + ((size_t)(n0 + c16) << 9);
            const ushort_t* Ah = Ab_r + 768;
            const int kbase = wv * 128 + quad * 8;
#pragma unroll
            for (int kk = 0; kk < 4; ++kk) {
                const int kcol = kbase + kk * 32;
                frag_ab bfr = *(const frag_ab*)&Wp[kcol];
                a0 = MFMA16(*(const frag_ab*)&Ah[c16 * 1280 + kcol], bfr, a0);
                a1 = MFMA16(*(const frag_ab*)&Ah[(16 + c16) * 1280 + kcol], bfr, a1);
            }
#pragma unroll
            for (int r = 0; r < 4; ++r) {
                scratch[wv * 512 + (quad * 4 + r) * 16 + c16] = a0[r];
                scratch[wv * 512 + (16 + quad * 4 + r) * 16 + c16] = a1[r];
            }
            __syncthreads();
#pragma unroll
            for (int h = 0; h < 2; ++h) {
                int idx = tid + h * 256;
                int m = idx >> 4, nl = idx & 15, n = n0 + nl;
                float v = scratch[m * 16 + nl] + scratch[512 + m * 16 + nl] +
                          scratch[1024 + m * 16 + nl] + scratch[1536 + m * 16 + nl];
                if (n < 256) att2_buf[m * 256 + n] = v + b_da[n];
                else gate_buf[m * 768 + n - 256] = sigf(v + b_fb[n - 256]);
            }
        }
        gbar(barcnt, bt += 256);

        // ============ S2: e + softmax + awe + gawe ============
        {
            const int b = g >> 3, dc = g & 7, d0 = dc * 96;
            scratch[tid] = att2_buf[b * 256 + tid];
            scratch[256 + tid] = w_fa[tid];
            __syncthreads();
            float ev = -3.0e38f;
            if (tid < Pz) {
                const ushort_t* ar = att1 + ((size_t)(b * Pz + tid) << 8);
                float s = 0.f;
#pragma unroll
                for (int j8 = 0; j8 < 256; j8 += 8) {
                    ushort8v v = *(const ushort8v*)&ar[j8];
#pragma unroll
                    for (int jj = 0; jj < 8; ++jj)
                        s += fmaxf(b2f(v[jj]) + scratch[j8 + jj], 0.f) * scratch[256 + j8 + jj];
                }
                ev = s + b_fa[0];
            }
            float mv = ev;
            for (int o = 32; o; o >>= 1) mv = fmaxf(mv, __shfl_down(mv, o, 64));
            if (lane == 0) scratch[512 + wv] = mv;
            __syncthreads();
            const float mx = fmaxf(fmaxf(scratch[512], scratch[513]), fmaxf(scratch[514], scratch[515]));
            float ex = (tid < Pz) ? __expf(ev - mx) : 0.f;
            float sv = ex;
            for (int o = 32; o; o >>= 1) sv += __shfl_down(sv, o, 64);
            if (lane == 0) scratch[516 + wv] = sv;
            __syncthreads();
            const float inv = 1.f / (scratch[516] + scratch[517] + scratch[518] + scratch[519]);
            if (tid < 200) scratch[768 + tid] = (tid < Pz) ? ex * inv : 0.f;
            __syncthreads();
            if (tid < 192) {
                const int d = d0 + (tid >> 1), half = tid & 1;
                const float4* rowp = (const float4*)(encT + ((size_t)(b * ENCz + d)) * 200);
                const float4* alp = (const float4*)&scratch[768];
                float4 a4 = {0.f, 0.f, 0.f, 0.f};
#pragma unroll
                for (int i = half * 25; i < half * 25 + 25; ++i) {
                    float4 e4 = rowp[i], l4 = alp[i];
                    a4.x += l4.x * e4.x; a4.y += l4.y * e4.y;
                    a4.z += l4.z * e4.z; a4.w += l4.w * e4.w;
                }
                float s = (a4.x + a4.y) + (a4.z + a4.w);
                s += __shfl_xor(s, 1, 64);
                if (half == 0) Ab_r[b * 1280 + d] = f2bf(s * gate_buf[b * 768 + d]);
            }
        }
        gbar(barcnt, bt += 256);

        // ============ S3: gates GEMM + LSTM ============
        {
            frag_cd pacc = (frag_cd){0.f, 0.f, 0.f, 0.f};
            const ushort_t* Ar = Ab_r + (size_t)(mh * 16 + c16) * 1280 + wv * 320 + quad * 8;
            const ushort_t* Wr = &Wl[c16][wv * 320 + quad * 8];
#pragma unroll
            for (int ks = 0; ks < 10; ++ks)
                pacc = MFMA16(*(const frag_ab*)(Ar + ks * 32), *(const frag_ab*)(Wr + ks * 32), pacc);
#pragma unroll
            for (int r = 0; r < 4; ++r) scratch[wv * 256 + (quad * 4 + r) * 16 + c16] = pacc[r];
            __syncthreads();
            {
                const int row = tid >> 4, col = tid & 15;
                float s = scratch[row * 16 + col] + scratch[256 + row * 16 + col] +
                          scratch[512 + row * 16 + col] + scratch[768 + row * 16 + col];
                s += Xih[(size_t)t * 65536 + (mh * 16 + row) * 2048 + ((col >> 2) << 9) + j0 + (col & 3)];
                scratch[1024 + row * 16 + col] = s;
            }
            __syncthreads();
            if (tid < 64) {
                const int bl = tid >> 2, jj = tid & 3;
                const int b = mh * 16 + bl, j = j0 + jj;
                const float iv = scratch[1024 + bl * 16 + jj], fv = scratch[1024 + bl * 16 + 4 + jj];
                const float gv = scratch[1024 + bl * 16 + 8 + jj], ov = scratch[1024 + bl * 16 + 12 + jj];
                const float cn = sigf(fv) * creg + sigf(iv) * tanhfast(gv);
                creg = cn;
                const float hn = sigf(ov) * tanhfast(cn);
                const ushort_t hb = f2bf(hn);
                Ab_w[b * 1280 + 768 + j] = hb;
                Hall[((size_t)t * 32 + b) * HIDz + j] = hb;
            }
        }
        if (t < Tz - 1) gbar(barcnt, bt += 256);
    }
}

// ---------- launcher ----------
extern "C" void kernel_launch(void* const* d_in, const int* in_sizes, int n_in,
                              void* d_out, int out_size, void* d_ws, size_t ws_size,
                              hipStream_t stream) {
    const float* enc   = (const float*)d_in[0];
    const int*   caps  = (const int*)d_in[1];
    const float* emb   = (const float*)d_in[2];
    const float* W_ea  = (const float*)d_in[3];
    const float* b_ea  = (const float*)d_in[4];
    const float* W_da  = (const float*)d_in[5];
    const float* b_da  = (const float*)d_in[6];
    const float* w_fa  = (const float*)d_in[7];
    const float* b_fa  = (const float*)d_in[8];
    const float* W_inh = (const float*)d_in[9];
    const float* b_inh = (const float*)d_in[10];
    const float* W_inc = (const float*)d_in[11];
    const float* b_inc = (const float*)d_in[12];
    const float* W_fb  = (const float*)d_in[13];
    const float* b_fb  = (const float*)d_in[14];
    const float* W_ih  = (const float*)d_in[15];
    const float* b_ih  = (const float*)d_in[16];
    const float* W_hh  = (const float*)d_in[17];
    const float* b_hh  = (const float*)d_in[18];
    const float* W_out = (const float*)d_in[19];
    const float* b_out = (const float*)d_in[20];

    char* ws = (char*)d_ws;
    ushort_t* att1    = (ushort_t*)(ws + 0);             // 6304x256 bf16      -> 3,227,648
    ushort_t* Xemb    = (ushort_t*)(ws + 3227648);       // 1280x512 bf16      -> 4,538,368
    ushort_t* encB    = (ushort_t*)(ws + 4538368);       // 6304x768 bf16      -> 14,221,312
    float*    Xih     = (float*)(ws + 14221312);         // 40x32x2048 fp32    -> 24,707,072
    float*    meanE   = (float*)(ws + 24707072);         // 32x768 fp32        -> 24,805,376
    float*    c_cur   = (float*)(ws + 24805376);         // 32x512 fp32        -> 24,870,912
    ushort_t* Abuf    = (ushort_t*)(ws + 24870912);      // 2 x 32x1280 bf16   -> 25,034,752
    float*    att2_buf= (float*)(ws + 25034752);         // 32x256 fp32        -> 25,067,520
    float*    gate_buf= (float*)(ws + 25067520);         // 32x768 fp32        -> 25,165,824
    ushort_t* Hall    = (ushort_t*)(ws + 25165824);      // 1280x512 bf16      -> 26,476,544
    ushort_t* WgT     = (ushort_t*)(ws + 26476544);      // 2048x1280 bf16     -> 31,719,424
    ushort_t* W_preT  = (ushort_t*)(ws + 31719424);      // 1024x512 bf16      -> 32,768,000
    ushort_t* W_eaT   = (ushort_t*)(ws + 32768000);      // 256x768 bf16       -> 33,161,216
    ushort_t* W_ihxT  = (ushort_t*)(ws + 33161216);      // 2048x512 bf16      -> 35,258,368
    ushort_t* W_outT  = (ushort_t*)(ws + 35258368);      // 32000x512 bf16     -> 68,026,368
    float*    encT    = (float*)(ws + 68026368);         // 32x768x200 fp32    -> 87,687,168
    unsigned* barcnt  = (unsigned*)(ws + 87687168);      // 16 B

    // precompute (order-independent, single stream)
    k_binit<<<1, 64, 0, stream>>>(barcnt);
    k_conv<<<2364, 256, 0, stream>>>(enc, encB);         // 32*197*768 = 2364*2048
    k_mean<<<96, 256, 0, stream>>>(enc, meanE);
    k_h0c0<<<128, 256, 0, stream>>>(meanE, W_inh, b_inh, W_inc, b_inc, c_cur, Abuf);
    k_gather<<<1280, 128, 0, stream>>>(caps, emb, Xemb);
    k_encT<<<dim3(24, 7, 32), 256, 0, stream>>>(enc, encT);
    k_transpose<<<dim3(8, 24), 256, 0, stream>>>(W_ea, 768, 256, W_eaT, 768, 0);
    k_transpose<<<dim3(64, 16), 256, 0, stream>>>(W_ih, 512, 2048, W_ihxT, 512, 0);
    k_transpose<<<dim3(64, 24), 256, 0, stream>>>(W_ih + 512 * 2048, 768, 2048, WgT, 1280, 0);
    k_transpose<<<dim3(64, 16), 256, 0, stream>>>(W_hh, 512, 2048, WgT, 1280, 768);
    k_transpose<<<dim3(8, 16), 256, 0, stream>>>(W_da, 512, 256, W_preT, 512, 0);
    k_transpose<<<dim3(24, 16), 256, 0, stream>>>(W_fb, 512, 768, W_preT + 256 * 512, 512, 0);
    k_transpose<<<dim3(1000, 16), 256, 0, stream>>>(W_out, 512, 32000, W_outT, 512, 0);

    // att1 = enc @ W_ea + b_ea   (bf16 out, row-major [b*197+p][256])
    k_gemm<1><<<dim3(2, 50), 256, 0, stream>>>(encB, 768, 6304, W_eaT, 768, b_ea, nullptr, att1, 256);
    // Xih = Xemb @ W_ih[:512] + b_ih + b_hh  (fp32 out)
    k_gemm<0><<<dim3(16, 10), 256, 0, stream>>>(Xemb, 512, 1280, W_ihxT, 512, b_ih, b_hh, Xih, 2048);

    // full 40-step recurrence: one persistent kernel, 3 custom barriers per step
    hipLaunchKernelGGL(k_recur, dim3(256), dim3(256), 0, stream,
                       att1, encT, W_preT, b_da, b_fb, w_fa, b_fa, WgT, Xih,
                       c_cur, Abuf, att2_buf, gate_buf, Hall, barcnt);

    // preds = Hall @ W_out + b_out -> d_out (B,T,V) fp32
    k_gemm<2><<<dim3(250, 10), 256, 0, stream>>>(Hall, 512, 1280, W_outT, 512, b_out, nullptr, d_out, VOCz);
}

// Round 4
// 2530.423 us; speedup vs baseline: 2.4781x; 1.0317x over previous
//
#include <hip/hip_runtime.h>

// ---------- problem constants ----------
#define Bz   32
#define Pz   197
#define ENCz 768
#define EMBz 512
#define HIDz 512
#define ATTz 256
#define VOCz 32000
#define Tz   40

#define NBLK 224

typedef unsigned short ushort_t;
typedef __attribute__((ext_vector_type(8))) short frag_ab;     // 8 bf16 (4 VGPRs)
typedef __attribute__((ext_vector_type(4))) float frag_cd;     // 4 fp32 acc
typedef __attribute__((ext_vector_type(4))) ushort_t ushort4v; // 8B
typedef __attribute__((ext_vector_type(8))) ushort_t ushort8v; // 16B

#define MFMA16(a, b, c) __builtin_amdgcn_mfma_f32_16x16x32_bf16((a), (b), (c), 0, 0, 0)

__device__ __forceinline__ float b2f(ushort_t u) {
    return __uint_as_float(((unsigned)u) << 16);
}
__device__ __forceinline__ ushort_t f2bf(float f) {
    unsigned u = __float_as_uint(f);
    unsigned r = (u + 0x7fffu + ((u >> 16) & 1u)) >> 16;
    return (ushort_t)r;
}
__device__ __forceinline__ float sigf(float x) { return 1.f / (1.f + __expf(-x)); }
__device__ __forceinline__ float tanhfast(float x) { return 1.f - 2.f / (__expf(2.f * x) + 1.f); }

// ---------- fast grid barrier (monotonic counter, device-scope) ----------
__device__ __forceinline__ void gbar(unsigned* cnt, unsigned target) {
    __syncthreads();
    if (threadIdx.x == 0) {
        __builtin_amdgcn_fence(__ATOMIC_RELEASE, "agent");
        __hip_atomic_fetch_add(cnt, 1u, __ATOMIC_RELAXED, __HIP_MEMORY_SCOPE_AGENT);
        while (__hip_atomic_load(cnt, __ATOMIC_RELAXED, __HIP_MEMORY_SCOPE_AGENT) < target) {
            __builtin_amdgcn_s_sleep(1);
        }
        __builtin_amdgcn_fence(__ATOMIC_ACQUIRE, "agent");
    }
    __syncthreads();
}

__global__ void k_binit(unsigned* c) { if (threadIdx.x == 0) *c = 0u; }

// ---------- fp32 -> bf16 bulk convert (8 elems/thread) ----------
__global__ __launch_bounds__(256) void k_conv(const float* __restrict__ in, ushort_t* __restrict__ out) {
    size_t base = ((size_t)blockIdx.x * 256 + threadIdx.x) * 8;
    const float4* src = (const float4*)(in + base);
    float4 a = src[0], b = src[1];
    ushort8v v;
    v[0] = f2bf(a.x); v[1] = f2bf(a.y); v[2] = f2bf(a.z); v[3] = f2bf(a.w);
    v[4] = f2bf(b.x); v[5] = f2bf(b.y); v[6] = f2bf(b.z); v[7] = f2bf(b.w);
    *(ushort8v*)(out + base) = v;
}

// ---------- mean over P ----------
__global__ __launch_bounds__(256) void k_mean(const float* __restrict__ enc, float* __restrict__ meanE) {
    int e = blockIdx.x * 256 + threadIdx.x;      // 32*768 = 24576
    int b = e / ENCz, d = e % ENCz;
    const float* p = enc + (size_t)b * Pz * ENCz + d;
    float s = 0.f;
    for (int i = 0; i < Pz; ++i) s += p[i * ENCz];
    meanE[e] = s * (1.f / (float)Pz);
}

// ---------- h0/c0 init (h0 bf16 lands in Abuf0 cols 768..1279) ----------
__global__ __launch_bounds__(256) void k_h0c0(const float* __restrict__ meanE,
                                              const float* __restrict__ W_inh, const float* __restrict__ b_inh,
                                              const float* __restrict__ W_inc, const float* __restrict__ b_inc,
                                              float* __restrict__ c_cur, ushort_t* __restrict__ Abuf) {
    __shared__ float msh[ENCz];
    int bid = blockIdx.x, tid = threadIdx.x;
    int b = bid >> 2, seg = bid & 3;             // seg0/1: h halves, seg2/3: c halves
    for (int i = tid; i < ENCz; i += 256) msh[i] = meanE[b * ENCz + i];
    __syncthreads();
    int col = (seg & 1) * 256 + tid;
    bool isc = (seg >> 1) != 0;
    const float* W = isc ? W_inc : W_inh;
    const float* bb = isc ? b_inc : b_inh;
    float a0 = 0.f, a1 = 0.f, a2 = 0.f, a3 = 0.f;
    for (int k = 0; k < ENCz; k += 4) {
        a0 += msh[k + 0] * W[(k + 0) * HIDz + col];
        a1 += msh[k + 1] * W[(k + 1) * HIDz + col];
        a2 += msh[k + 2] * W[(k + 2) * HIDz + col];
        a3 += msh[k + 3] * W[(k + 3) * HIDz + col];
    }
    float acc = a0 + a1 + a2 + a3 + bb[col];
    if (isc) c_cur[b * HIDz + col] = acc;
    else Abuf[b * 1280 + 768 + col] = f2bf(acc);
}

// ---------- embedding gather+convert ----------
__global__ __launch_bounds__(128) void k_gather(const int* __restrict__ captions, const float* __restrict__ emb,
                                                ushort_t* __restrict__ Xemb) {
    int row = blockIdx.x;                        // 0..1279 = t*32+b
    int t = row >> 5, b = row & 31;
    int cap = captions[b * 41 + t];
    float4 f = *(const float4*)(emb + (size_t)cap * EMBz + threadIdx.x * 4);
    ushort4v v; v[0] = f2bf(f.x); v[1] = f2bf(f.y); v[2] = f2bf(f.z); v[3] = f2bf(f.w);
    *(ushort4v*)(Xemb + (size_t)row * EMBz + threadIdx.x * 4) = v;
}

// ---------- fp32-in / bf16-out transpose ----------
__global__ __launch_bounds__(256) void k_transpose(const float* __restrict__ in, int R, int C,
                                                   ushort_t* __restrict__ out, int ldo, int koff) {
    __shared__ ushort_t tile[32][33];
    int c0 = blockIdx.x * 32, r0 = blockIdx.y * 32;
    int tx = threadIdx.x & 31, ty = threadIdx.x >> 5;    // ty 0..7
#pragma unroll
    for (int i = 0; i < 4; ++i) {
        int r = r0 + ty + i * 8;
        tile[ty + i * 8][tx] = f2bf(in[(size_t)r * C + c0 + tx]);
    }
    __syncthreads();
#pragma unroll
    for (int i = 0; i < 4; ++i) {
        int c = c0 + ty + i * 8;
        out[(size_t)c * ldo + koff + r0 + tx] = tile[tx][ty + i * 8];
    }
}

// ---------- enc transpose to bf16: encTb[b][d][p], p padded to 200 (pad=0) ----------
__global__ __launch_bounds__(256) void k_encTb(const float* __restrict__ enc, ushort_t* __restrict__ encTb) {
    __shared__ float tile[32][33];
    int b = blockIdx.z;
    int d0 = blockIdx.x * 32, p0 = blockIdx.y * 32;
    int tx = threadIdx.x & 31, ty = threadIdx.x >> 5;
#pragma unroll
    for (int i = 0; i < 4; ++i) {
        int p = p0 + ty + i * 8;
        tile[ty + i * 8][tx] = (p < Pz) ? enc[((size_t)b * Pz + p) * ENCz + d0 + tx] : 0.f;
    }
    __syncthreads();
#pragma unroll
    for (int i = 0; i < 4; ++i) {
        int d = d0 + ty + i * 8, p = p0 + tx;
        if (p < 200) encTb[((size_t)b * ENCz + d) * 200 + p] = f2bf(tile[tx][ty + i * 8]);
    }
}

// ---------- MFMA GEMM ----------
// MODE 0: fp32 out (ldo), bias1+bias2;  MODE 1: bf16 out (ldo), bias1, row-guard
// MODE 2: fp32 out permuted for final preds (row m=t*32+b -> out[b][t][n]), XCD-swizzled grid
template <int MODE>
__global__ __launch_bounds__(256) void k_gemm(const ushort_t* __restrict__ A, int lda, int M,
                                              const ushort_t* __restrict__ BT, int K,
                                              const float* __restrict__ B1, const float* __restrict__ B2,
                                              void* __restrict__ out, int ldo) {
    __shared__ __align__(16) ushort_t As[128 * 64];
    __shared__ __align__(16) ushort_t Bs[128 * 64];
    const int tid = threadIdx.x;
    const int lane = tid & 63, w = tid >> 6;
    const int wm = w >> 1, wn = w & 1;
    int n0, m0;
    if (MODE == 2) {
        const int total = gridDim.x * gridDim.y;
        const int lin = blockIdx.y * gridDim.x + blockIdx.x;
        const int q = total >> 3, r = total - (q << 3);
        const int xcd = lin & 7, slot = lin >> 3;
        const int L = (xcd < r) ? xcd * (q + 1) + slot : r * (q + 1) + (xcd - r) * q + slot;
        const int nIdx = L / (int)gridDim.y;
        n0 = nIdx * 128; m0 = (L - nIdx * (int)gridDim.y) * 128;
    } else {
        n0 = blockIdx.x * 128; m0 = blockIdx.y * 128;
    }
    const int quad = lane >> 4, c16 = lane & 15;

    frag_cd acc[4][4];
#pragma unroll
    for (int i = 0; i < 4; ++i)
#pragma unroll
        for (int j = 0; j < 4; ++j) acc[i][j] = (frag_cd){0.f, 0.f, 0.f, 0.f};

    for (int k0 = 0; k0 < K; k0 += 64) {
#pragma unroll
        for (int it = 0; it < 4; ++it) {
            int c = tid + it * 256;              // chunk 0..1023
            int row = c >> 3, col8 = (c & 7) * 8;
            int gr = m0 + row; gr = gr < M ? gr : M - 1;
            *(frag_ab*)&As[row * 64 + col8] = *(const frag_ab*)&A[(size_t)gr * lda + k0 + col8];
            *(frag_ab*)&Bs[row * 64 + col8] = *(const frag_ab*)&BT[(size_t)(n0 + row) * K + k0 + col8];
        }
        __syncthreads();
#pragma unroll
        for (int kk = 0; kk < 64; kk += 32) {
            int kcol = kk + quad * 8;
            frag_ab af[4], bf[4];
#pragma unroll
            for (int i = 0; i < 4; ++i) af[i] = *(const frag_ab*)&As[(wm * 64 + i * 16 + c16) * 64 + kcol];
#pragma unroll
            for (int j = 0; j < 4; ++j) bf[j] = *(const frag_ab*)&Bs[(wn * 64 + j * 16 + c16) * 64 + kcol];
#pragma unroll
            for (int i = 0; i < 4; ++i)
#pragma unroll
                for (int j = 0; j < 4; ++j) acc[i][j] = MFMA16(af[i], bf[j], acc[i][j]);
        }
        __syncthreads();
    }

#pragma unroll
    for (int i = 0; i < 4; ++i) {
#pragma unroll
        for (int j = 0; j < 4; ++j) {
            int n = n0 + wn * 64 + j * 16 + c16;
            float bias = B1[n];
            if (B2 != nullptr) bias += B2[n];
#pragma unroll
            for (int r = 0; r < 4; ++r) {
                int m = m0 + wm * 64 + i * 16 + quad * 4 + r;
                float v = acc[i][j][r] + bias;
                if (MODE == 0) {
                    if (m < M) ((float*)out)[(size_t)m * ldo + n] = v;
                } else if (MODE == 1) {
                    if (m < M) ((ushort_t*)out)[(size_t)m * ldo + n] = f2bf(v);
                } else {
                    int b = m & 31, t = m >> 5;
                    ((float*)out)[(size_t)b * (Tz * VOCz) + (size_t)t * VOCz + n] = v;
                }
            }
        }
    }
}

// ---------- awe helper: one (b,dc) task from an LDS enc slice ----------
__device__ __forceinline__ void do_awe(int task, const ushort_t* encS, float* scratch,
                                       const float* gate_buf, const float* alpha_buf,
                                       ushort_t* Ab_r, int tid) {
    const int b = task >> 3, d0 = (task & 7) * 96;
    if (tid < 200) scratch[tid] = alpha_buf[b * 200 + tid];
    __syncthreads();
    if (tid < 192) {
        const int d = tid >> 1, h = tid & 1;
        const int c0 = h ? 13 : 0, c1 = h ? 25 : 13;
        float s = 0.f;
        for (int c = c0; c < c1; ++c) {
            ushort8v v = *(const ushort8v*)&encS[d * 200 + c * 8];
#pragma unroll
            for (int jj = 0; jj < 8; ++jj) s += b2f(v[jj]) * scratch[c * 8 + jj];
        }
        s += __shfl_xor(s, 1, 64);
        if (h == 0) Ab_r[b * 1280 + d0 + d] = f2bf(s * gate_buf[b * 768 + d0 + d]);
    }
    __syncthreads();
}

// ---------- persistent recurrence kernel (224 blocks: residency margin) ----------
// Roles: g<64:    S1 (att2/gate MFMA, WpreL in LDS) + awe(g) + S3(cols g*4)
//        64..127: awe(g) + awe(192+(g-64)) + S3(cols g*4)
//        128..191: awe(g)
//        192..223: ESET — att1[b] in LDS, e + softmax -> alpha (non-redundant)
// S3: 128 blocks, each computes ALL 32 batch rows x 16 gate-cols (two MFMA chains).
// 4 barriers/step; steady-state operands in LDS so fences stay cheap.
__global__ __launch_bounds__(256, 1) void k_recur(
    const ushort_t* __restrict__ att1, const ushort_t* __restrict__ encTb,
    const ushort_t* __restrict__ W_preT, const float* __restrict__ b_da,
    const float* __restrict__ b_fb, const float* __restrict__ w_fa,
    const float* __restrict__ b_fa, const ushort_t* __restrict__ WgT,
    const float* __restrict__ Xih, const float* __restrict__ c0,
    ushort_t* __restrict__ Abuf, float* __restrict__ att2_buf,
    float* __restrict__ gate_buf, float* __restrict__ alpha_buf,
    ushort_t* __restrict__ Hall, unsigned* __restrict__ barcnt)
{
    __shared__ __align__(16) char smem[126208];
    float* scratch = (float*)smem;                             // 2048 floats = 8,192 B
    char* R = smem + 8192;                                     // role-specific region

    const int g = (int)blockIdx.x;
    const int tid = (int)threadIdx.x;
    const int lane = tid & 63, wv = tid >> 6;
    const int quad = lane >> 4, c16 = lane & 15;

    const bool isS3 = (g < 128);
    const bool isS1 = (g < 64);
    const bool isE  = (g >= 192);
    const int j0 = g << 2;                                     // S3 cols (g<128)

    ushort_t (*Wl)[1288] = (ushort_t(*)[1288])R;               // S3: 41,216 B
    ushort_t* WpreL = (ushort_t*)(R + 41216);                  // S1: [16][520] = 16,640 B
    ushort_t* enc0  = isS1 ? (ushort_t*)(R + 57856)
                    : (isS3 ? (ushort_t*)(R + 41216) : (ushort_t*)R);  // [96][200] = 38,400 B
    ushort_t* enc1  = (ushort_t*)(R + 79616);                  // blocks 64..127 only
    ushort_t* att1L = (ushort_t*)R;                            // ESET: [197][264] = 104,016 B

    // ---- one-time staging ----
    if (isS3) {                                                // Wl: 16 Wg cols
        int r = tid >> 4, ch = tid & 15;
        int coln = ((r >> 2) << 9) + j0 + (r & 3);
        const ushort_t* src = WgT + (size_t)coln * 1280 + ch * 80;
        ushort_t* dst = &Wl[r][ch * 80];
#pragma unroll
        for (int i = 0; i < 10; ++i)
            *(ushort8v*)(dst + i * 8) = *(const ushort8v*)(src + i * 8);
    }
    if (isS1) {
        const int n0 = g << 4;
#pragma unroll
        for (int i = 0; i < 4; ++i) {
            int c = tid + i * 256;                             // 1024 chunks of 16B
            int r = c >> 6, col8 = (c & 63) * 8;
            *(ushort8v*)&WpreL[r * 520 + col8] = *(const ushort8v*)&W_preT[(size_t)(n0 + r) * 512 + col8];
        }
    }
    if (!isE) {
        const ushort_t* src = encTb + ((size_t)((g >> 3) * 768 + (g & 7) * 96)) * 200;
        for (int i = 0; i < 10; ++i) {
            int c = tid + i * 256;
            if (c < 2400) *(ushort8v*)&enc0[c * 8] = *(const ushort8v*)&src[c * 8];
        }
        if (g >= 64 && g < 128) {
            int task1 = 192 + (g - 64);
            const ushort_t* src1 = encTb + ((size_t)((task1 >> 3) * 768 + (task1 & 7) * 96)) * 200;
            for (int i = 0; i < 10; ++i) {
                int c = tid + i * 256;
                if (c < 2400) *(ushort8v*)&enc1[c * 8] = *(const ushort8v*)&src1[c * 8];
            }
        }
    } else {
        const int eb = g - 192;
        for (int i = 0; i < 25; ++i) {
            int c = tid + i * 256;                             // 6304 chunks of 16B
            if (c < 6304) {
                int p = c >> 5, off = (c & 31) * 8;
                *(ushort8v*)&att1L[p * 264 + off] = *(const ushort8v*)&att1[((size_t)(eb * Pz + p)) * 256 + off];
            }
        }
    }
    float creg = 0.f;
    if (isS3 && tid < 128) creg = c0[(tid >> 2) * HIDz + j0 + (tid & 3)];
    __syncthreads();

    unsigned bt = 0;
    for (int t = 0; t < Tz; ++t) {
        ushort_t* Ab_r = Abuf + (size_t)(t & 1) * 40960;
        ushort_t* Ab_w = Abuf + (size_t)((t + 1) & 1) * 40960;

        // ============ S1: pre-GEMM (att2 + gate) ============
        if (isS1) {
            const int n0 = g << 4;
            frag_cd a0 = (frag_cd){0.f, 0.f, 0.f, 0.f};
            frag_cd a1 = (frag_cd){0.f, 0.f, 0.f, 0.f};
            const ushort_t* Wp = WpreL + (size_t)c16 * 520;
            const ushort_t* Ah = Ab_r + 768;
            const int kbase = wv * 128 + quad * 8;
#pragma unroll
            for (int kk = 0; kk < 4; ++kk) {
                const int kcol = kbase + kk * 32;
                frag_ab bfr = *(const frag_ab*)&Wp[kcol];
                a0 = MFMA16(*(const frag_ab*)&Ah[c16 * 1280 + kcol], bfr, a0);
                a1 = MFMA16(*(const frag_ab*)&Ah[(16 + c16) * 1280 + kcol], bfr, a1);
            }
#pragma unroll
            for (int r = 0; r < 4; ++r) {
                scratch[wv * 512 + (quad * 4 + r) * 16 + c16] = a0[r];
                scratch[wv * 512 + 256 + (quad * 4 + r) * 16 + c16] = a1[r];
            }
            __syncthreads();
#pragma unroll
            for (int h = 0; h < 2; ++h) {
                int idx = tid + h * 256;
                int m = idx >> 4, nl = idx & 15, n = n0 + nl;
                int base = (m >> 4) * 256 + (m & 15) * 16 + nl;
                float v = scratch[base] + scratch[512 + base] +
                          scratch[1024 + base] + scratch[1536 + base];
                if (n < 256) att2_buf[m * 256 + n] = v + b_da[n];
                else gate_buf[m * 768 + n - 256] = sigf(v + b_fb[n - 256]);
            }
        }
        gbar(barcnt, bt += NBLK);

        // ============ S2a: e + softmax -> alpha (ESET only) ============
        if (isE) {
            const int eb = g - 192;
            scratch[tid] = att2_buf[eb * 256 + tid];
            scratch[256 + tid] = w_fa[tid];
            __syncthreads();
            float ev = -3.0e38f;
            if (tid < Pz) {
                const ushort_t* ar = att1L + tid * 264;
                float s = 0.f;
#pragma unroll
                for (int j8 = 0; j8 < 256; j8 += 8) {
                    ushort8v v = *(const ushort8v*)&ar[j8];
#pragma unroll
                    for (int jj = 0; jj < 8; ++jj)
                        s += fmaxf(b2f(v[jj]) + scratch[j8 + jj], 0.f) * scratch[256 + j8 + jj];
                }
                ev = s + b_fa[0];
            }
            float mv = ev;
            for (int o = 32; o; o >>= 1) mv = fmaxf(mv, __shfl_down(mv, o, 64));
            if (lane == 0) scratch[512 + wv] = mv;
            __syncthreads();
            const float mx = fmaxf(fmaxf(scratch[512], scratch[513]), fmaxf(scratch[514], scratch[515]));
            float ex = (tid < Pz) ? __expf(ev - mx) : 0.f;
            float sv = ex;
            for (int o = 32; o; o >>= 1) sv += __shfl_down(sv, o, 64);
            if (lane == 0) scratch[516 + wv] = sv;
            __syncthreads();
            const float inv = 1.f / (scratch[516] + scratch[517] + scratch[518] + scratch[519]);
            if (tid < 200) alpha_buf[eb * 200 + tid] = ex * inv;
        }
        gbar(barcnt, bt += NBLK);

        // ============ S2b: awe + gate -> gawe (bf16 into Ab_r) ============
        if (!isE) {
            do_awe(g, enc0, scratch, gate_buf, alpha_buf, Ab_r, tid);
            if (g >= 64 && g < 128)
                do_awe(192 + (g - 64), enc1, scratch, gate_buf, alpha_buf, Ab_r, tid);
        }
        gbar(barcnt, bt += NBLK);

        // ============ S3: gates GEMM (32 rows x 16 cols) + LSTM ============
        if (isS3) {
            frag_cd p0 = (frag_cd){0.f, 0.f, 0.f, 0.f};
            frag_cd p1 = (frag_cd){0.f, 0.f, 0.f, 0.f};
            const ushort_t* Ar0 = Ab_r + (size_t)c16 * 1280 + wv * 320 + quad * 8;
            const ushort_t* Ar1 = Ar0 + 16 * 1280;
            const ushort_t* Wr = &Wl[c16][wv * 320 + quad * 8];
#pragma unroll
            for (int ks = 0; ks < 10; ++ks) {
                frag_ab bfr = *(const frag_ab*)(Wr + ks * 32);
                p0 = MFMA16(*(const frag_ab*)(Ar0 + ks * 32), bfr, p0);
                p1 = MFMA16(*(const frag_ab*)(Ar1 + ks * 32), bfr, p1);
            }
#pragma unroll
            for (int r = 0; r < 4; ++r) {
                scratch[wv * 512 + (quad * 4 + r) * 16 + c16] = p0[r];
                scratch[wv * 512 + 256 + (quad * 4 + r) * 16 + c16] = p1[r];
            }
            __syncthreads();
            float s0, s1;
            {
                const int mr = tid >> 4, col = tid & 15;
                const int base = mr * 16 + col;
                const int xcol = ((col >> 2) << 9) + j0 + (col & 3);
                s0 = scratch[base] + scratch[512 + base] + scratch[1024 + base] + scratch[1536 + base]
                   + Xih[(size_t)t * 65536 + mr * 2048 + xcol];
                s1 = scratch[256 + base] + scratch[768 + base] + scratch[1280 + base] + scratch[1792 + base]
                   + Xih[(size_t)t * 65536 + (16 + mr) * 2048 + xcol];
            }
            __syncthreads();
            scratch[tid] = s0;
            scratch[256 + tid] = s1;
            __syncthreads();
            if (tid < 128) {
                const int bl = tid >> 2, jj = tid & 3, j = j0 + jj;
                const float iv = scratch[bl * 16 + jj], fv = scratch[bl * 16 + 4 + jj];
                const float gv = scratch[bl * 16 + 8 + jj], ov = scratch[bl * 16 + 12 + jj];
                const float cn = sigf(fv) * creg + sigf(iv) * tanhfast(gv);
                creg = cn;
                const float hn = sigf(ov) * tanhfast(cn);
                const ushort_t hb = f2bf(hn);
                Ab_w[bl * 1280 + 768 + j] = hb;
                Hall[((size_t)t * 32 + bl) * HIDz + j] = hb;
            }
        }
        if (t < Tz - 1) gbar(barcnt, bt += NBLK);
    }
}

// ---------- launcher ----------
extern "C" void kernel_launch(void* const* d_in, const int* in_sizes, int n_in,
                              void* d_out, int out_size, void* d_ws, size_t ws_size,
                              hipStream_t stream) {
    const float* enc   = (const float*)d_in[0];
    const int*   caps  = (const int*)d_in[1];
    const float* emb   = (const float*)d_in[2];
    const float* W_ea  = (const float*)d_in[3];
    const float* b_ea  = (const float*)d_in[4];
    const float* W_da  = (const float*)d_in[5];
    const float* b_da  = (const float*)d_in[6];
    const float* w_fa  = (const float*)d_in[7];
    const float* b_fa  = (const float*)d_in[8];
    const float* W_inh = (const float*)d_in[9];
    const float* b_inh = (const float*)d_in[10];
    const float* W_inc = (const float*)d_in[11];
    const float* b_inc = (const float*)d_in[12];
    const float* W_fb  = (const float*)d_in[13];
    const float* b_fb  = (const float*)d_in[14];
    const float* W_ih  = (const float*)d_in[15];
    const float* b_ih  = (const float*)d_in[16];
    const float* W_hh  = (const float*)d_in[17];
    const float* b_hh  = (const float*)d_in[18];
    const float* W_out = (const float*)d_in[19];
    const float* b_out = (const float*)d_in[20];

    char* ws = (char*)d_ws;
    ushort_t* att1     = (ushort_t*)(ws + 0);            // 6304x256 bf16     -> 3,227,648
    ushort_t* Xemb     = (ushort_t*)(ws + 3227648);      // 1280x512 bf16     -> 4,538,368
    ushort_t* encB     = (ushort_t*)(ws + 4538368);      // 6304x768 bf16     -> 14,221,312
    float*    Xih      = (float*)(ws + 14221312);        // 40x32x2048 fp32   -> 24,707,072
    float*    meanE    = (float*)(ws + 24707072);        // 32x768 fp32       -> 24,805,376
    float*    c_cur    = (float*)(ws + 24805376);        // 32x512 fp32       -> 24,870,912
    ushort_t* Abuf     = (ushort_t*)(ws + 24870912);     // 2 x 32x1280 bf16  -> 25,034,752
    float*    att2_buf = (float*)(ws + 25034752);        // 32x256 fp32       -> 25,067,520
    float*    gate_buf = (float*)(ws + 25067520);        // 32x768 fp32       -> 25,165,824
    float*    alpha_buf= (float*)(ws + 25165824);        // 32x200 fp32       -> 25,191,424
    ushort_t* Hall     = (ushort_t*)(ws + 25191424);     // 1280x512 bf16     -> 26,502,144
    ushort_t* WgT      = (ushort_t*)(ws + 26502144);     // 2048x1280 bf16    -> 31,745,024
    ushort_t* W_preT   = (ushort_t*)(ws + 31745024);     // 1024x512 bf16     -> 32,793,600
    ushort_t* W_eaT    = (ushort_t*)(ws + 32793600);     // 256x768 bf16      -> 33,186,816
    ushort_t* W_ihxT   = (ushort_t*)(ws + 33186816);     // 2048x512 bf16     -> 35,283,968
    ushort_t* W_outT   = (ushort_t*)(ws + 35283968);     // 32000x512 bf16    -> 68,051,968
    ushort_t* encTb    = (ushort_t*)(ws + 68051968);     // 32x768x200 bf16   -> 77,882,368
    unsigned* barcnt   = (unsigned*)(ws + 77882368);     // 64 B

    // precompute (order-independent, single stream)
    k_binit<<<1, 64, 0, stream>>>(barcnt);
    k_conv<<<2364, 256, 0, stream>>>(enc, encB);         // 32*197*768 = 2364*2048
    k_mean<<<96, 256, 0, stream>>>(enc, meanE);
    k_h0c0<<<128, 256, 0, stream>>>(meanE, W_inh, b_inh, W_inc, b_inc, c_cur, Abuf);
    k_gather<<<1280, 128, 0, stream>>>(caps, emb, Xemb);
    k_encTb<<<dim3(24, 7, 32), 256, 0, stream>>>(enc, encTb);
    k_transpose<<<dim3(8, 24), 256, 0, stream>>>(W_ea, 768, 256, W_eaT, 768, 0);
    k_transpose<<<dim3(64, 16), 256, 0, stream>>>(W_ih, 512, 2048, W_ihxT, 512, 0);
    k_transpose<<<dim3(64, 24), 256, 0, stream>>>(W_ih + 512 * 2048, 768, 2048, WgT, 1280, 0);
    k_transpose<<<dim3(64, 16), 256, 0, stream>>>(W_hh, 512, 2048, WgT, 1280, 768);
    k_transpose<<<dim3(8, 16), 256, 0, stream>>>(W_da, 512, 256, W_preT, 512, 0);
    k_transpose<<<dim3(24, 16), 256, 0, stream>>>(W_fb, 512, 768, W_preT + 256 * 512, 512, 0);
    k_transpose<<<dim3(1000, 16), 256, 0, stream>>>(W_out, 512, 32000, W_outT, 512, 0);

    // att1 = enc @ W_ea + b_ea   (bf16 out, row-major [b*197+p][256])
    k_gemm<1><<<dim3(2, 50), 256, 0, stream>>>(encB, 768, 6304, W_eaT, 768, b_ea, nullptr, att1, 256);
    // Xih = Xemb @ W_ih[:512] + b_ih + b_hh  (fp32 out)
    k_gemm<0><<<dim3(16, 10), 256, 0, stream>>>(Xemb, 512, 1280, W_ihxT, 512, b_ih, b_hh, Xih, 2048);

    // full 40-step recurrence: one persistent kernel (224 blocks), 4 barriers/step
    hipLaunchKernelGGL(k_recur, dim3(NBLK), dim3(256), 0, stream,
                       att1, encTb, W_preT, b_da, b_fb, w_fa, b_fa, WgT, Xih,
                       c_cur, Abuf, att2_buf, gate_buf, alpha_buf, Hall, barcnt);

    // preds = Hall @ W_out + b_out -> d_out (B,T,V) fp32
    k_gemm<2><<<dim3(250, 10), 256, 0, stream>>>(Hall, 512, 1280, W_outT, 512, b_out, nullptr, d_out, VOCz);
}

// Round 5
// 1916.519 us; speedup vs baseline: 3.2719x; 1.3203x over previous
//
#include <hip/hip_runtime.h>

// ---------- problem constants ----------
#define Bz   32
#define Pz   197
#define ENCz 768
#define EMBz 512
#define HIDz 512
#define ATTz 256
#define VOCz 32000
#define Tz   40

#define NBLK 224

typedef unsigned short ushort_t;
typedef __attribute__((ext_vector_type(8))) short frag_ab;     // 8 bf16 (4 VGPRs)
typedef __attribute__((ext_vector_type(4))) float frag_cd;     // 4 fp32 acc
typedef __attribute__((ext_vector_type(4))) ushort_t ushort4v; // 8B
typedef __attribute__((ext_vector_type(8))) ushort_t ushort8v; // 16B

#define MFMA16(a, b, c) __builtin_amdgcn_mfma_f32_16x16x32_bf16((a), (b), (c), 0, 0, 0)

__device__ __forceinline__ float b2f(ushort_t u) {
    return __uint_as_float(((unsigned)u) << 16);
}
__device__ __forceinline__ ushort_t f2bf(float f) {
    unsigned u = __float_as_uint(f);
    unsigned r = (u + 0x7fffu + ((u >> 16) & 1u)) >> 16;
    return (ushort_t)r;
}
__device__ __forceinline__ float sigf(float x) { return 1.f / (1.f + __expf(-x)); }
__device__ __forceinline__ float tanhfast(float x) { return 1.f - 2.f / (__expf(2.f * x) + 1.f); }

// ---------- decontended all-observe grid barrier ----------
// Per-block epoch flags, 128 B apart (no shared line, no RMW). Arrival: release-fence +
// relaxed store of this block's flag. Join: threads 0..NBLK-1 each poll one flag.
__device__ __forceinline__ void gbar(unsigned* flags, unsigned ep, int g, int tid) {
    __syncthreads();
    if (tid == 0) {
        __builtin_amdgcn_fence(__ATOMIC_RELEASE, "agent");
        __hip_atomic_store(&flags[g << 5], ep, __ATOMIC_RELAXED, __HIP_MEMORY_SCOPE_AGENT);
    }
    if (tid < NBLK) {
        while (__hip_atomic_load(&flags[tid << 5], __ATOMIC_RELAXED, __HIP_MEMORY_SCOPE_AGENT) < ep)
            __builtin_amdgcn_s_sleep(1);
    }
    __syncthreads();
    if (tid == 0) __builtin_amdgcn_fence(__ATOMIC_ACQUIRE, "agent");
    __syncthreads();
}

__global__ void k_binit(unsigned* f) {
    for (int i = threadIdx.x; i < NBLK * 32; i += 256) f[i] = 0u;
}

// ---------- fp32 -> bf16 bulk convert (8 elems/thread) ----------
__global__ __launch_bounds__(256) void k_conv(const float* __restrict__ in, ushort_t* __restrict__ out) {
    size_t base = ((size_t)blockIdx.x * 256 + threadIdx.x) * 8;
    const float4* src = (const float4*)(in + base);
    float4 a = src[0], b = src[1];
    ushort8v v;
    v[0] = f2bf(a.x); v[1] = f2bf(a.y); v[2] = f2bf(a.z); v[3] = f2bf(a.w);
    v[4] = f2bf(b.x); v[5] = f2bf(b.y); v[6] = f2bf(b.z); v[7] = f2bf(b.w);
    *(ushort8v*)(out + base) = v;
}

// ---------- mean over P ----------
__global__ __launch_bounds__(256) void k_mean(const float* __restrict__ enc, float* __restrict__ meanE) {
    int e = blockIdx.x * 256 + threadIdx.x;      // 32*768 = 24576
    int b = e / ENCz, d = e % ENCz;
    const float* p = enc + (size_t)b * Pz * ENCz + d;
    float s = 0.f;
    for (int i = 0; i < Pz; ++i) s += p[i * ENCz];
    meanE[e] = s * (1.f / (float)Pz);
}

// ---------- h0/c0 init (h0 bf16 lands in Abuf0 cols 768..1279) ----------
__global__ __launch_bounds__(256) void k_h0c0(const float* __restrict__ meanE,
                                              const float* __restrict__ W_inh, const float* __restrict__ b_inh,
                                              const float* __restrict__ W_inc, const float* __restrict__ b_inc,
                                              float* __restrict__ c_cur, ushort_t* __restrict__ Abuf) {
    __shared__ float msh[ENCz];
    int bid = blockIdx.x, tid = threadIdx.x;
    int b = bid >> 2, seg = bid & 3;             // seg0/1: h halves, seg2/3: c halves
    for (int i = tid; i < ENCz; i += 256) msh[i] = meanE[b * ENCz + i];
    __syncthreads();
    int col = (seg & 1) * 256 + tid;
    bool isc = (seg >> 1) != 0;
    const float* W = isc ? W_inc : W_inh;
    const float* bb = isc ? b_inc : b_inh;
    float a0 = 0.f, a1 = 0.f, a2 = 0.f, a3 = 0.f;
    for (int k = 0; k < ENCz; k += 4) {
        a0 += msh[k + 0] * W[(k + 0) * HIDz + col];
        a1 += msh[k + 1] * W[(k + 1) * HIDz + col];
        a2 += msh[k + 2] * W[(k + 2) * HIDz + col];
        a3 += msh[k + 3] * W[(k + 3) * HIDz + col];
    }
    float acc = a0 + a1 + a2 + a3 + bb[col];
    if (isc) c_cur[b * HIDz + col] = acc;
    else Abuf[b * 1280 + 768 + col] = f2bf(acc);
}

// ---------- embedding gather+convert ----------
__global__ __launch_bounds__(128) void k_gather(const int* __restrict__ captions, const float* __restrict__ emb,
                                                ushort_t* __restrict__ Xemb) {
    int row = blockIdx.x;                        // 0..1279 = t*32+b
    int t = row >> 5, b = row & 31;
    int cap = captions[b * 41 + t];
    float4 f = *(const float4*)(emb + (size_t)cap * EMBz + threadIdx.x * 4);
    ushort4v v; v[0] = f2bf(f.x); v[1] = f2bf(f.y); v[2] = f2bf(f.z); v[3] = f2bf(f.w);
    *(ushort4v*)(Xemb + (size_t)row * EMBz + threadIdx.x * 4) = v;
}

// ---------- fp32-in / bf16-out transpose ----------
__global__ __launch_bounds__(256) void k_transpose(const float* __restrict__ in, int R, int C,
                                                   ushort_t* __restrict__ out, int ldo, int koff) {
    __shared__ ushort_t tile[32][33];
    int c0 = blockIdx.x * 32, r0 = blockIdx.y * 32;
    int tx = threadIdx.x & 31, ty = threadIdx.x >> 5;    // ty 0..7
#pragma unroll
    for (int i = 0; i < 4; ++i) {
        int r = r0 + ty + i * 8;
        tile[ty + i * 8][tx] = f2bf(in[(size_t)r * C + c0 + tx]);
    }
    __syncthreads();
#pragma unroll
    for (int i = 0; i < 4; ++i) {
        int c = c0 + ty + i * 8;
        out[(size_t)c * ldo + koff + r0 + tx] = tile[tx][ty + i * 8];
    }
}

// ---------- enc transpose to bf16: encTb[b][d][p], p padded to 200 (pad=0) ----------
__global__ __launch_bounds__(256) void k_encTb(const float* __restrict__ enc, ushort_t* __restrict__ encTb) {
    __shared__ float tile[32][33];
    int b = blockIdx.z;
    int d0 = blockIdx.x * 32, p0 = blockIdx.y * 32;
    int tx = threadIdx.x & 31, ty = threadIdx.x >> 5;
#pragma unroll
    for (int i = 0; i < 4; ++i) {
        int p = p0 + ty + i * 8;
        tile[ty + i * 8][tx] = (p < Pz) ? enc[((size_t)b * Pz + p) * ENCz + d0 + tx] : 0.f;
    }
    __syncthreads();
#pragma unroll
    for (int i = 0; i < 4; ++i) {
        int d = d0 + ty + i * 8, p = p0 + tx;
        if (p < 200) encTb[((size_t)b * ENCz + d) * 200 + p] = f2bf(tile[tx][ty + i * 8]);
    }
}

// ---------- MFMA GEMM ----------
// MODE 0: fp32 out (ldo), bias1+bias2;  MODE 1: bf16 out (ldo), bias1, row-guard
// MODE 2: fp32 out permuted for final preds (row m=t*32+b -> out[b][t][n]), XCD-swizzled grid
template <int MODE>
__global__ __launch_bounds__(256) void k_gemm(const ushort_t* __restrict__ A, int lda, int M,
                                              const ushort_t* __restrict__ BT, int K,
                                              const float* __restrict__ B1, const float* __restrict__ B2,
                                              void* __restrict__ out, int ldo) {
    __shared__ __align__(16) ushort_t As[128 * 64];
    __shared__ __align__(16) ushort_t Bs[128 * 64];
    const int tid = threadIdx.x;
    const int lane = tid & 63, w = tid >> 6;
    const int wm = w >> 1, wn = w & 1;
    int n0, m0;
    if (MODE == 2) {
        const int total = gridDim.x * gridDim.y;
        const int lin = blockIdx.y * gridDim.x + blockIdx.x;
        const int q = total >> 3, r = total - (q << 3);
        const int xcd = lin & 7, slot = lin >> 3;
        const int L = (xcd < r) ? xcd * (q + 1) + slot : r * (q + 1) + (xcd - r) * q + slot;
        const int nIdx = L / (int)gridDim.y;
        n0 = nIdx * 128; m0 = (L - nIdx * (int)gridDim.y) * 128;
    } else {
        n0 = blockIdx.x * 128; m0 = blockIdx.y * 128;
    }
    const int quad = lane >> 4, c16 = lane & 15;

    frag_cd acc[4][4];
#pragma unroll
    for (int i = 0; i < 4; ++i)
#pragma unroll
        for (int j = 0; j < 4; ++j) acc[i][j] = (frag_cd){0.f, 0.f, 0.f, 0.f};

    for (int k0 = 0; k0 < K; k0 += 64) {
#pragma unroll
        for (int it = 0; it < 4; ++it) {
            int c = tid + it * 256;              // chunk 0..1023
            int row = c >> 3, col8 = (c & 7) * 8;
            int gr = m0 + row; gr = gr < M ? gr : M - 1;
            *(frag_ab*)&As[row * 64 + col8] = *(const frag_ab*)&A[(size_t)gr * lda + k0 + col8];
            *(frag_ab*)&Bs[row * 64 + col8] = *(const frag_ab*)&BT[(size_t)(n0 + row) * K + k0 + col8];
        }
        __syncthreads();
#pragma unroll
        for (int kk = 0; kk < 64; kk += 32) {
            int kcol = kk + quad * 8;
            frag_ab af[4], bf[4];
#pragma unroll
            for (int i = 0; i < 4; ++i) af[i] = *(const frag_ab*)&As[(wm * 64 + i * 16 + c16) * 64 + kcol];
#pragma unroll
            for (int j = 0; j < 4; ++j) bf[j] = *(const frag_ab*)&Bs[(wn * 64 + j * 16 + c16) * 64 + kcol];
#pragma unroll
            for (int i = 0; i < 4; ++i)
#pragma unroll
                for (int j = 0; j < 4; ++j) acc[i][j] = MFMA16(af[i], bf[j], acc[i][j]);
        }
        __syncthreads();
    }

#pragma unroll
    for (int i = 0; i < 4; ++i) {
#pragma unroll
        for (int j = 0; j < 4; ++j) {
            int n = n0 + wn * 64 + j * 16 + c16;
            float bias = B1[n];
            if (B2 != nullptr) bias += B2[n];
#pragma unroll
            for (int r = 0; r < 4; ++r) {
                int m = m0 + wm * 64 + i * 16 + quad * 4 + r;
                float v = acc[i][j][r] + bias;
                if (MODE == 0) {
                    if (m < M) ((float*)out)[(size_t)m * ldo + n] = v;
                } else if (MODE == 1) {
                    if (m < M) ((ushort_t*)out)[(size_t)m * ldo + n] = f2bf(v);
                } else {
                    int b = m & 31, t = m >> 5;
                    ((float*)out)[(size_t)b * (Tz * VOCz) + (size_t)t * VOCz + n] = v;
                }
            }
        }
    }
}

// ---------- awe helper: one (b,dc) task from an LDS enc slice ----------
__device__ __forceinline__ void do_awe(int task, const ushort_t* encS, float* scratch,
                                       const float* gate_buf, const float* alpha_buf,
                                       ushort_t* Ab_r, int tid) {
    const int b = task >> 3, d0 = (task & 7) * 96;
    if (tid < 200) scratch[tid] = alpha_buf[b * 200 + tid];
    __syncthreads();
    if (tid < 192) {
        const int d = tid >> 1, h = tid & 1;
        const int c0 = h ? 13 : 0, c1 = h ? 25 : 13;
        float s = 0.f;
        for (int c = c0; c < c1; ++c) {
            ushort8v v = *(const ushort8v*)&encS[d * 200 + c * 8];
#pragma unroll
            for (int jj = 0; jj < 8; ++jj) s += b2f(v[jj]) * scratch[c * 8 + jj];
        }
        s += __shfl_xor(s, 1, 64);
        if (h == 0) Ab_r[b * 1280 + d0 + d] = f2bf(s * gate_buf[b * 768 + d0 + d]);
    }
    __syncthreads();
}

// ---------- persistent recurrence kernel (224 blocks: residency margin) ----------
// Roles: g<64:    S1 (att2/gate MFMA, WpreL in LDS) + awe(g) + S3(cols g*4)
//        64..127: awe(g) + awe(192+(g-64)) + S3(cols g*4)
//        128..191: awe(g)
//        192..223: ESET — att1[b] in LDS, e + softmax -> alpha (non-redundant)
// S3: 128 blocks, each computes ALL 32 batch rows x 16 gate-cols (two MFMA chains).
// 4 barriers/step; steady-state operands in LDS so fences stay cheap.
__global__ __launch_bounds__(256, 1) void k_recur(
    const ushort_t* __restrict__ att1, const ushort_t* __restrict__ encTb,
    const ushort_t* __restrict__ W_preT, const float* __restrict__ b_da,
    const float* __restrict__ b_fb, const float* __restrict__ w_fa,
    const float* __restrict__ b_fa, const ushort_t* __restrict__ WgT,
    const float* __restrict__ Xih, const float* __restrict__ c0,
    ushort_t* __restrict__ Abuf, float* __restrict__ att2_buf,
    float* __restrict__ gate_buf, float* __restrict__ alpha_buf,
    ushort_t* __restrict__ Hall, unsigned* __restrict__ barflags)
{
    __shared__ __align__(16) char smem[126208];
    float* scratch = (float*)smem;                             // 2048 floats = 8,192 B
    char* R = smem + 8192;                                     // role-specific region

    const int g = (int)blockIdx.x;
    const int tid = (int)threadIdx.x;
    const int lane = tid & 63, wv = tid >> 6;
    const int quad = lane >> 4, c16 = lane & 15;

    const bool isS3 = (g < 128);
    const bool isS1 = (g < 64);
    const bool isE  = (g >= 192);
    const int j0 = g << 2;                                     // S3 cols (g<128)

    ushort_t (*Wl)[1288] = (ushort_t(*)[1288])R;               // S3: 41,216 B
    ushort_t* WpreL = (ushort_t*)(R + 41216);                  // S1: [16][520] = 16,640 B
    ushort_t* enc0  = isS1 ? (ushort_t*)(R + 57856)
                    : (isS3 ? (ushort_t*)(R + 41216) : (ushort_t*)R);  // [96][200] = 38,400 B
    ushort_t* enc1  = (ushort_t*)(R + 79616);                  // blocks 64..127 only
    ushort_t* att1L = (ushort_t*)R;                            // ESET: [197][264] = 104,016 B

    // ---- one-time staging ----
    if (isS3) {                                                // Wl: 16 Wg cols
        int r = tid >> 4, ch = tid & 15;
        int coln = ((r >> 2) << 9) + j0 + (r & 3);
        const ushort_t* src = WgT + (size_t)coln * 1280 + ch * 80;
        ushort_t* dst = &Wl[r][ch * 80];
#pragma unroll
        for (int i = 0; i < 10; ++i)
            *(ushort8v*)(dst + i * 8) = *(const ushort8v*)(src + i * 8);
    }
    if (isS1) {
        const int n0 = g << 4;
#pragma unroll
        for (int i = 0; i < 4; ++i) {
            int c = tid + i * 256;                             // 1024 chunks of 16B
            int r = c >> 6, col8 = (c & 63) * 8;
            *(ushort8v*)&WpreL[r * 520 + col8] = *(const ushort8v*)&W_preT[(size_t)(n0 + r) * 512 + col8];
        }
    }
    if (!isE) {
        const ushort_t* src = encTb + ((size_t)((g >> 3) * 768 + (g & 7) * 96)) * 200;
        for (int i = 0; i < 10; ++i) {
            int c = tid + i * 256;
            if (c < 2400) *(ushort8v*)&enc0[c * 8] = *(const ushort8v*)&src[c * 8];
        }
        if (g >= 64 && g < 128) {
            int task1 = 192 + (g - 64);
            const ushort_t* src1 = encTb + ((size_t)((task1 >> 3) * 768 + (task1 & 7) * 96)) * 200;
            for (int i = 0; i < 10; ++i) {
                int c = tid + i * 256;
                if (c < 2400) *(ushort8v*)&enc1[c * 8] = *(const ushort8v*)&src1[c * 8];
            }
        }
    } else {
        const int eb = g - 192;
        for (int i = 0; i < 25; ++i) {
            int c = tid + i * 256;                             // 6304 chunks of 16B
            if (c < 6304) {
                int p = c >> 5, off = (c & 31) * 8;
                *(ushort8v*)&att1L[p * 264 + off] = *(const ushort8v*)&att1[((size_t)(eb * Pz + p)) * 256 + off];
            }
        }
    }
    float creg = 0.f;
    if (isS3 && tid < 128) creg = c0[(tid >> 2) * HIDz + j0 + (tid & 3)];
    __syncthreads();

    unsigned bt = 0;
    for (int t = 0; t < Tz; ++t) {
        ushort_t* Ab_r = Abuf + (size_t)(t & 1) * 40960;
        ushort_t* Ab_w = Abuf + (size_t)((t + 1) & 1) * 40960;

        // ============ S1: pre-GEMM (att2 + gate) ============
        if (isS1) {
            const int n0 = g << 4;
            frag_cd a0 = (frag_cd){0.f, 0.f, 0.f, 0.f};
            frag_cd a1 = (frag_cd){0.f, 0.f, 0.f, 0.f};
            const ushort_t* Wp = WpreL + (size_t)c16 * 520;
            const ushort_t* Ah = Ab_r + 768;
            const int kbase = wv * 128 + quad * 8;
#pragma unroll
            for (int kk = 0; kk < 4; ++kk) {
                const int kcol = kbase + kk * 32;
                frag_ab bfr = *(const frag_ab*)&Wp[kcol];
                a0 = MFMA16(*(const frag_ab*)&Ah[c16 * 1280 + kcol], bfr, a0);
                a1 = MFMA16(*(const frag_ab*)&Ah[(16 + c16) * 1280 + kcol], bfr, a1);
            }
#pragma unroll
            for (int r = 0; r < 4; ++r) {
                scratch[wv * 512 + (quad * 4 + r) * 16 + c16] = a0[r];
                scratch[wv * 512 + 256 + (quad * 4 + r) * 16 + c16] = a1[r];
            }
            __syncthreads();
#pragma unroll
            for (int h = 0; h < 2; ++h) {
                int idx = tid + h * 256;
                int m = idx >> 4, nl = idx & 15, n = n0 + nl;
                int base = (m >> 4) * 256 + (m & 15) * 16 + nl;
                float v = scratch[base] + scratch[512 + base] +
                          scratch[1024 + base] + scratch[1536 + base];
                if (n < 256) att2_buf[m * 256 + n] = v + b_da[n];
                else gate_buf[m * 768 + n - 256] = sigf(v + b_fb[n - 256]);
            }
        }
        gbar(barflags, ++bt, g, tid);

        // ============ S2a: e + softmax -> alpha (ESET only) ============
        if (isE) {
            const int eb = g - 192;
            scratch[tid] = att2_buf[eb * 256 + tid];
            scratch[256 + tid] = w_fa[tid];
            __syncthreads();
            float ev = -3.0e38f;
            if (tid < Pz) {
                const ushort_t* ar = att1L + tid * 264;
                float s = 0.f;
#pragma unroll
                for (int j8 = 0; j8 < 256; j8 += 8) {
                    ushort8v v = *(const ushort8v*)&ar[j8];
#pragma unroll
                    for (int jj = 0; jj < 8; ++jj)
                        s += fmaxf(b2f(v[jj]) + scratch[j8 + jj], 0.f) * scratch[256 + j8 + jj];
                }
                ev = s + b_fa[0];
            }
            float mv = ev;
            for (int o = 32; o; o >>= 1) mv = fmaxf(mv, __shfl_down(mv, o, 64));
            if (lane == 0) scratch[512 + wv] = mv;
            __syncthreads();
            const float mx = fmaxf(fmaxf(scratch[512], scratch[513]), fmaxf(scratch[514], scratch[515]));
            float ex = (tid < Pz) ? __expf(ev - mx) : 0.f;
            float sv = ex;
            for (int o = 32; o; o >>= 1) sv += __shfl_down(sv, o, 64);
            if (lane == 0) scratch[516 + wv] = sv;
            __syncthreads();
            const float inv = 1.f / (scratch[516] + scratch[517] + scratch[518] + scratch[519]);
            if (tid < 200) alpha_buf[eb * 200 + tid] = ex * inv;
        }
        gbar(barflags, ++bt, g, tid);

        // ============ S2b: awe + gate -> gawe (bf16 into Ab_r) ============
        if (!isE) {
            do_awe(g, enc0, scratch, gate_buf, alpha_buf, Ab_r, tid);
            if (g >= 64 && g < 128)
                do_awe(192 + (g - 64), enc1, scratch, gate_buf, alpha_buf, Ab_r, tid);
        }
        gbar(barflags, ++bt, g, tid);

        // ============ S3: gates GEMM (32 rows x 16 cols) + LSTM ============
        if (isS3) {
            frag_cd p0 = (frag_cd){0.f, 0.f, 0.f, 0.f};
            frag_cd p1 = (frag_cd){0.f, 0.f, 0.f, 0.f};
            const ushort_t* Ar0 = Ab_r + (size_t)c16 * 1280 + wv * 320 + quad * 8;
            const ushort_t* Ar1 = Ar0 + 16 * 1280;
            const ushort_t* Wr = &Wl[c16][wv * 320 + quad * 8];
#pragma unroll
            for (int ks = 0; ks < 10; ++ks) {
                frag_ab bfr = *(const frag_ab*)(Wr + ks * 32);
                p0 = MFMA16(*(const frag_ab*)(Ar0 + ks * 32), bfr, p0);
                p1 = MFMA16(*(const frag_ab*)(Ar1 + ks * 32), bfr, p1);
            }
#pragma unroll
            for (int r = 0; r < 4; ++r) {
                scratch[wv * 512 + (quad * 4 + r) * 16 + c16] = p0[r];
                scratch[wv * 512 + 256 + (quad * 4 + r) * 16 + c16] = p1[r];
            }
            __syncthreads();
            float s0, s1;
            {
                const int mr = tid >> 4, col = tid & 15;
                const int base = mr * 16 + col;
                const int xcol = ((col >> 2) << 9) + j0 + (col & 3);
                s0 = scratch[base] + scratch[512 + base] + scratch[1024 + base] + scratch[1536 + base]
                   + Xih[(size_t)t * 65536 + mr * 2048 + xcol];
                s1 = scratch[256 + base] + scratch[768 + base] + scratch[1280 + base] + scratch[1792 + base]
                   + Xih[(size_t)t * 65536 + (16 + mr) * 2048 + xcol];
            }
            __syncthreads();
            scratch[tid] = s0;
            scratch[256 + tid] = s1;
            __syncthreads();
            if (tid < 128) {
                const int bl = tid >> 2, jj = tid & 3, j = j0 + jj;
                const float iv = scratch[bl * 16 + jj], fv = scratch[bl * 16 + 4 + jj];
                const float gv = scratch[bl * 16 + 8 + jj], ov = scratch[bl * 16 + 12 + jj];
                const float cn = sigf(fv) * creg + sigf(iv) * tanhfast(gv);
                creg = cn;
                const float hn = sigf(ov) * tanhfast(cn);
                const ushort_t hb = f2bf(hn);
                Ab_w[bl * 1280 + 768 + j] = hb;
                Hall[((size_t)t * 32 + bl) * HIDz + j] = hb;
            }
        }
        if (t < Tz - 1) gbar(barflags, ++bt, g, tid);
    }
}

// ---------- launcher ----------
extern "C" void kernel_launch(void* const* d_in, const int* in_sizes, int n_in,
                              void* d_out, int out_size, void* d_ws, size_t ws_size,
                              hipStream_t stream) {
    const float* enc   = (const float*)d_in[0];
    const int*   caps  = (const int*)d_in[1];
    const float* emb   = (const float*)d_in[2];
    const float* W_ea  = (const float*)d_in[3];
    const float* b_ea  = (const float*)d_in[4];
    const float* W_da  = (const float*)d_in[5];
    const float* b_da  = (const float*)d_in[6];
    const float* w_fa  = (const float*)d_in[7];
    const float* b_fa  = (const float*)d_in[8];
    const float* W_inh = (const float*)d_in[9];
    const float* b_inh = (const float*)d_in[10];
    const float* W_inc = (const float*)d_in[11];
    const float* b_inc = (const float*)d_in[12];
    const float* W_fb  = (const float*)d_in[13];
    const float* b_fb  = (const float*)d_in[14];
    const float* W_ih  = (const float*)d_in[15];
    const float* b_ih  = (const float*)d_in[16];
    const float* W_hh  = (const float*)d_in[17];
    const float* b_hh  = (const float*)d_in[18];
    const float* W_out = (const float*)d_in[19];
    const float* b_out = (const float*)d_in[20];

    char* ws = (char*)d_ws;
    ushort_t* att1     = (ushort_t*)(ws + 0);            // 6304x256 bf16     -> 3,227,648
    ushort_t* Xemb     = (ushort_t*)(ws + 3227648);      // 1280x512 bf16     -> 4,538,368
    ushort_t* encB     = (ushort_t*)(ws + 4538368);      // 6304x768 bf16     -> 14,221,312
    float*    Xih      = (float*)(ws + 14221312);        // 40x32x2048 fp32   -> 24,707,072
    float*    meanE    = (float*)(ws + 24707072);        // 32x768 fp32       -> 24,805,376
    float*    c_cur    = (float*)(ws + 24805376);        // 32x512 fp32       -> 24,870,912
    ushort_t* Abuf     = (ushort_t*)(ws + 24870912);     // 2 x 32x1280 bf16  -> 25,034,752
    float*    att2_buf = (float*)(ws + 25034752);        // 32x256 fp32       -> 25,067,520
    float*    gate_buf = (float*)(ws + 25067520);        // 32x768 fp32       -> 25,165,824
    float*    alpha_buf= (float*)(ws + 25165824);        // 32x200 fp32       -> 25,191,424
    ushort_t* Hall     = (ushort_t*)(ws + 25191424);     // 1280x512 bf16     -> 26,502,144
    ushort_t* WgT      = (ushort_t*)(ws + 26502144);     // 2048x1280 bf16    -> 31,745,024
    ushort_t* W_preT   = (ushort_t*)(ws + 31745024);     // 1024x512 bf16     -> 32,793,600
    ushort_t* W_eaT    = (ushort_t*)(ws + 32793600);     // 256x768 bf16      -> 33,186,816
    ushort_t* W_ihxT   = (ushort_t*)(ws + 33186816);     // 2048x512 bf16     -> 35,283,968
    ushort_t* W_outT   = (ushort_t*)(ws + 35283968);     // 32000x512 bf16    -> 68,051,968
    ushort_t* encTb    = (ushort_t*)(ws + 68051968);     // 32x768x200 bf16   -> 77,882,368
    unsigned* barflags = (unsigned*)(ws + 77882368);     // 224 x 128 B = 28,672 B

    // precompute (order-independent, single stream)
    k_binit<<<1, 256, 0, stream>>>(barflags);
    k_conv<<<2364, 256, 0, stream>>>(enc, encB);         // 32*197*768 = 2364*2048
    k_mean<<<96, 256, 0, stream>>>(enc, meanE);
    k_h0c0<<<128, 256, 0, stream>>>(meanE, W_inh, b_inh, W_inc, b_inc, c_cur, Abuf);
    k_gather<<<1280, 128, 0, stream>>>(caps, emb, Xemb);
    k_encTb<<<dim3(24, 7, 32), 256, 0, stream>>>(enc, encTb);
    k_transpose<<<dim3(8, 24), 256, 0, stream>>>(W_ea, 768, 256, W_eaT, 768, 0);
    k_transpose<<<dim3(64, 16), 256, 0, stream>>>(W_ih, 512, 2048, W_ihxT, 512, 0);
    k_transpose<<<dim3(64, 24), 256, 0, stream>>>(W_ih + 512 * 2048, 768, 2048, WgT, 1280, 0);
    k_transpose<<<dim3(64, 16), 256, 0, stream>>>(W_hh, 512, 2048, WgT, 1280, 768);
    k_transpose<<<dim3(8, 16), 256, 0, stream>>>(W_da, 512, 256, W_preT, 512, 0);
    k_transpose<<<dim3(24, 16), 256, 0, stream>>>(W_fb, 512, 768, W_preT + 256 * 512, 512, 0);
    k_transpose<<<dim3(1000, 16), 256, 0, stream>>>(W_out, 512, 32000, W_outT, 512, 0);

    // att1 = enc @ W_ea + b_ea   (bf16 out, row-major [b*197+p][256])
    k_gemm<1><<<dim3(2, 50), 256, 0, stream>>>(encB, 768, 6304, W_eaT, 768, b_ea, nullptr, att1, 256);
    // Xih = Xemb @ W_ih[:512] + b_ih + b_hh  (fp32 out)
    k_gemm<0><<<dim3(16, 10), 256, 0, stream>>>(Xemb, 512, 1280, W_ihxT, 512, b_ih, b_hh, Xih, 2048);

    // full 40-step recurrence: one persistent kernel (224 blocks), 4 barriers/step
    hipLaunchKernelGGL(k_recur, dim3(NBLK), dim3(256), 0, stream,
                       att1, encTb, W_preT, b_da, b_fb, w_fa, b_fa, WgT, Xih,
                       c_cur, Abuf, att2_buf, gate_buf, alpha_buf, Hall, barflags);

    // preds = Hall @ W_out + b_out -> d_out (B,T,V) fp32
    k_gemm<2><<<dim3(250, 10), 256, 0, stream>>>(Hall, 512, 1280, W_outT, 512, b_out, nullptr, d_out, VOCz);
}

// Round 6
// 1394.383 us; speedup vs baseline: 4.4971x; 1.3745x over previous
//
#include <hip/hip_runtime.h>

// ---------- problem constants ----------
#define Bz   32
#define Pz   197
#define ENCz 768
#define EMBz 512
#define HIDz 512
#define ATTz 256
#define VOCz 32000
#define Tz   40

#define NBLK 224

typedef unsigned short ushort_t;
typedef __attribute__((ext_vector_type(8))) short frag_ab;     // 8 bf16 (4 VGPRs)
typedef __attribute__((ext_vector_type(4))) float frag_cd;     // 4 fp32 acc
typedef __attribute__((ext_vector_type(4))) ushort_t ushort4v; // 8B
typedef __attribute__((ext_vector_type(8))) ushort_t ushort8v; // 16B

#define MFMA16(a, b, c) __builtin_amdgcn_mfma_f32_16x16x32_bf16((a), (b), (c), 0, 0, 0)

__device__ __forceinline__ float b2f(ushort_t u) {
    return __uint_as_float(((unsigned)u) << 16);
}
__device__ __forceinline__ ushort_t f2bf(float f) {
    unsigned u = __float_as_uint(f);
    unsigned r = (u + 0x7fffu + ((u >> 16) & 1u)) >> 16;
    return (ushort_t)r;
}
__device__ __forceinline__ float sigf(float x) { return 1.f / (1.f + __expf(-x)); }
__device__ __forceinline__ float tanhfast(float x) { return 1.f - 2.f / (__expf(2.f * x) + 1.f); }

// ---------- uncached (agent-coherent) access helpers ----------
__device__ __forceinline__ void st_f32(float* p, float v) {
    __hip_atomic_store(p, v, __ATOMIC_RELAXED, __HIP_MEMORY_SCOPE_AGENT);
}
__device__ __forceinline__ float ld_f32(const float* p) {
    return __hip_atomic_load(p, __ATOMIC_RELAXED, __HIP_MEMORY_SCOPE_AGENT);
}
__device__ __forceinline__ void st_u32(unsigned* p, unsigned v) {
    __hip_atomic_store(p, v, __ATOMIC_RELAXED, __HIP_MEMORY_SCOPE_AGENT);
}
__device__ __forceinline__ unsigned ld_u32(const unsigned* p) {
    return __hip_atomic_load(p, __ATOMIC_RELAXED, __HIP_MEMORY_SCOPE_AGENT);
}
// 16B bf16 fragment via two 8B agent-scope loads (coherent, bypasses stale L2)
__device__ __forceinline__ frag_ab ldfrag(const ushort_t* p) {
    union { frag_ab f; unsigned long long q[2]; } u;
    u.q[0] = __hip_atomic_load((const unsigned long long*)p, __ATOMIC_RELAXED, __HIP_MEMORY_SCOPE_AGENT);
    u.q[1] = __hip_atomic_load((const unsigned long long*)(p + 4), __ATOMIC_RELAXED, __HIP_MEMORY_SCOPE_AGENT);
    return u.f;
}

// ---------- fence-free grid barrier ----------
// All cross-block data moves via agent-scope atomics (LLC-coherent, no L2 residency),
// so no wbl2/invalidate fences are needed. __syncthreads drains each wave's vmcnt
// (compiler emits s_waitcnt before s_barrier), so arrival implies stores are visible.
__device__ __forceinline__ void gbar(unsigned* flags, unsigned ep, int g, int tid) {
    __syncthreads();
    if (tid == 0) {
        asm volatile("s_waitcnt vmcnt(0)" ::: "memory");
        __hip_atomic_store(&flags[g << 5], ep, __ATOMIC_RELAXED, __HIP_MEMORY_SCOPE_AGENT);
    }
    if (tid < NBLK) {
        while (__hip_atomic_load(&flags[tid << 5], __ATOMIC_RELAXED, __HIP_MEMORY_SCOPE_AGENT) < ep)
            __builtin_amdgcn_s_sleep(1);
    }
    __syncthreads();
}

__global__ void k_binit(unsigned* f) {
    for (int i = threadIdx.x; i < NBLK * 32; i += 256) f[i] = 0u;
}

// ---------- fp32 -> bf16 bulk convert (8 elems/thread) ----------
__global__ __launch_bounds__(256) void k_conv(const float* __restrict__ in, ushort_t* __restrict__ out) {
    size_t base = ((size_t)blockIdx.x * 256 + threadIdx.x) * 8;
    const float4* src = (const float4*)(in + base);
    float4 a = src[0], b = src[1];
    ushort8v v;
    v[0] = f2bf(a.x); v[1] = f2bf(a.y); v[2] = f2bf(a.z); v[3] = f2bf(a.w);
    v[4] = f2bf(b.x); v[5] = f2bf(b.y); v[6] = f2bf(b.z); v[7] = f2bf(b.w);
    *(ushort8v*)(out + base) = v;
}

// ---------- mean over P ----------
__global__ __launch_bounds__(256) void k_mean(const float* __restrict__ enc, float* __restrict__ meanE) {
    int e = blockIdx.x * 256 + threadIdx.x;      // 32*768 = 24576
    int b = e / ENCz, d = e % ENCz;
    const float* p = enc + (size_t)b * Pz * ENCz + d;
    float s = 0.f;
    for (int i = 0; i < Pz; ++i) s += p[i * ENCz];
    meanE[e] = s * (1.f / (float)Pz);
}

// ---------- h0/c0 init (h0 bf16 lands in Abuf0 cols 768..1279) ----------
__global__ __launch_bounds__(256) void k_h0c0(const float* __restrict__ meanE,
                                              const float* __restrict__ W_inh, const float* __restrict__ b_inh,
                                              const float* __restrict__ W_inc, const float* __restrict__ b_inc,
                                              float* __restrict__ c_cur, ushort_t* __restrict__ Abuf) {
    __shared__ float msh[ENCz];
    int bid = blockIdx.x, tid = threadIdx.x;
    int b = bid >> 2, seg = bid & 3;             // seg0/1: h halves, seg2/3: c halves
    for (int i = tid; i < ENCz; i += 256) msh[i] = meanE[b * ENCz + i];
    __syncthreads();
    int col = (seg & 1) * 256 + tid;
    bool isc = (seg >> 1) != 0;
    const float* W = isc ? W_inc : W_inh;
    const float* bb = isc ? b_inc : b_inh;
    float a0 = 0.f, a1 = 0.f, a2 = 0.f, a3 = 0.f;
    for (int k = 0; k < ENCz; k += 4) {
        a0 += msh[k + 0] * W[(k + 0) * HIDz + col];
        a1 += msh[k + 1] * W[(k + 1) * HIDz + col];
        a2 += msh[k + 2] * W[(k + 2) * HIDz + col];
        a3 += msh[k + 3] * W[(k + 3) * HIDz + col];
    }
    float acc = a0 + a1 + a2 + a3 + bb[col];
    if (isc) c_cur[b * HIDz + col] = acc;
    else Abuf[b * 1280 + 768 + col] = f2bf(acc);
}

// ---------- embedding gather+convert ----------
__global__ __launch_bounds__(128) void k_gather(const int* __restrict__ captions, const float* __restrict__ emb,
                                                ushort_t* __restrict__ Xemb) {
    int row = blockIdx.x;                        // 0..1279 = t*32+b
    int t = row >> 5, b = row & 31;
    int cap = captions[b * 41 + t];
    float4 f = *(const float4*)(emb + (size_t)cap * EMBz + threadIdx.x * 4);
    ushort4v v; v[0] = f2bf(f.x); v[1] = f2bf(f.y); v[2] = f2bf(f.z); v[3] = f2bf(f.w);
    *(ushort4v*)(Xemb + (size_t)row * EMBz + threadIdx.x * 4) = v;
}

// ---------- fp32-in / bf16-out transpose ----------
__global__ __launch_bounds__(256) void k_transpose(const float* __restrict__ in, int R, int C,
                                                   ushort_t* __restrict__ out, int ldo, int koff) {
    __shared__ ushort_t tile[32][33];
    int c0 = blockIdx.x * 32, r0 = blockIdx.y * 32;
    int tx = threadIdx.x & 31, ty = threadIdx.x >> 5;    // ty 0..7
#pragma unroll
    for (int i = 0; i < 4; ++i) {
        int r = r0 + ty + i * 8;
        tile[ty + i * 8][tx] = f2bf(in[(size_t)r * C + c0 + tx]);
    }
    __syncthreads();
#pragma unroll
    for (int i = 0; i < 4; ++i) {
        int c = c0 + ty + i * 8;
        out[(size_t)c * ldo + koff + r0 + tx] = tile[tx][ty + i * 8];
    }
}

// ---------- enc transpose to bf16: encTb[b][d][p], p padded to 200 (pad=0) ----------
__global__ __launch_bounds__(256) void k_encTb(const float* __restrict__ enc, ushort_t* __restrict__ encTb) {
    __shared__ float tile[32][33];
    int b = blockIdx.z;
    int d0 = blockIdx.x * 32, p0 = blockIdx.y * 32;
    int tx = threadIdx.x & 31, ty = threadIdx.x >> 5;
#pragma unroll
    for (int i = 0; i < 4; ++i) {
        int p = p0 + ty + i * 8;
        tile[ty + i * 8][tx] = (p < Pz) ? enc[((size_t)b * Pz + p) * ENCz + d0 + tx] : 0.f;
    }
    __syncthreads();
#pragma unroll
    for (int i = 0; i < 4; ++i) {
        int d = d0 + ty + i * 8, p = p0 + tx;
        if (p < 200) encTb[((size_t)b * ENCz + d) * 200 + p] = f2bf(tile[tx][ty + i * 8]);
    }
}

// ---------- MFMA GEMM ----------
// MODE 0: fp32 out (ldo), bias1+bias2;  MODE 1: bf16 out (ldo), bias1, row-guard
// MODE 2: fp32 out permuted for final preds (row m=t*32+b -> out[b][t][n]), XCD-swizzled grid
template <int MODE>
__global__ __launch_bounds__(256) void k_gemm(const ushort_t* __restrict__ A, int lda, int M,
                                              const ushort_t* __restrict__ BT, int K,
                                              const float* __restrict__ B1, const float* __restrict__ B2,
                                              void* __restrict__ out, int ldo) {
    __shared__ __align__(16) ushort_t As[128 * 64];
    __shared__ __align__(16) ushort_t Bs[128 * 64];
    const int tid = threadIdx.x;
    const int lane = tid & 63, w = tid >> 6;
    const int wm = w >> 1, wn = w & 1;
    int n0, m0;
    if (MODE == 2) {
        const int total = gridDim.x * gridDim.y;
        const int lin = blockIdx.y * gridDim.x + blockIdx.x;
        const int q = total >> 3, r = total - (q << 3);
        const int xcd = lin & 7, slot = lin >> 3;
        const int L = (xcd < r) ? xcd * (q + 1) + slot : r * (q + 1) + (xcd - r) * q + slot;
        const int nIdx = L / (int)gridDim.y;
        n0 = nIdx * 128; m0 = (L - nIdx * (int)gridDim.y) * 128;
    } else {
        n0 = blockIdx.x * 128; m0 = blockIdx.y * 128;
    }
    const int quad = lane >> 4, c16 = lane & 15;

    frag_cd acc[4][4];
#pragma unroll
    for (int i = 0; i < 4; ++i)
#pragma unroll
        for (int j = 0; j < 4; ++j) acc[i][j] = (frag_cd){0.f, 0.f, 0.f, 0.f};

    for (int k0 = 0; k0 < K; k0 += 64) {
#pragma unroll
        for (int it = 0; it < 4; ++it) {
            int c = tid + it * 256;              // chunk 0..1023
            int row = c >> 3, col8 = (c & 7) * 8;
            int gr = m0 + row; gr = gr < M ? gr : M - 1;
            *(frag_ab*)&As[row * 64 + col8] = *(const frag_ab*)&A[(size_t)gr * lda + k0 + col8];
            *(frag_ab*)&Bs[row * 64 + col8] = *(const frag_ab*)&BT[(size_t)(n0 + row) * K + k0 + col8];
        }
        __syncthreads();
#pragma unroll
        for (int kk = 0; kk < 64; kk += 32) {
            int kcol = kk + quad * 8;
            frag_ab af[4], bf[4];
#pragma unroll
            for (int i = 0; i < 4; ++i) af[i] = *(const frag_ab*)&As[(wm * 64 + i * 16 + c16) * 64 + kcol];
#pragma unroll
            for (int j = 0; j < 4; ++j) bf[j] = *(const frag_ab*)&Bs[(wn * 64 + j * 16 + c16) * 64 + kcol];
#pragma unroll
            for (int i = 0; i < 4; ++i)
#pragma unroll
                for (int j = 0; j < 4; ++j) acc[i][j] = MFMA16(af[i], bf[j], acc[i][j]);
        }
        __syncthreads();
    }

#pragma unroll
    for (int i = 0; i < 4; ++i) {
#pragma unroll
        for (int j = 0; j < 4; ++j) {
            int n = n0 + wn * 64 + j * 16 + c16;
            float bias = B1[n];
            if (B2 != nullptr) bias += B2[n];
#pragma unroll
            for (int r = 0; r < 4; ++r) {
                int m = m0 + wm * 64 + i * 16 + quad * 4 + r;
                float v = acc[i][j][r] + bias;
                if (MODE == 0) {
                    if (m < M) ((float*)out)[(size_t)m * ldo + n] = v;
                } else if (MODE == 1) {
                    if (m < M) ((ushort_t*)out)[(size_t)m * ldo + n] = f2bf(v);
                } else {
                    int b = m & 31, t = m >> 5;
                    ((float*)out)[(size_t)b * (Tz * VOCz) + (size_t)t * VOCz + n] = v;
                }
            }
        }
    }
}

// ---------- awe helper: one (b,dc) task from an LDS enc slice ----------
__device__ __forceinline__ void do_awe(int task, const ushort_t* encS, float* scratch,
                                       const float* gate_buf, const float* alpha_buf,
                                       ushort_t* Ab_r, int tid) {
    const int b = task >> 3, d0 = (task & 7) * 96;
    if (tid < 200) scratch[tid] = ld_f32(&alpha_buf[b * 200 + tid]);
    __syncthreads();
    if (tid < 192) {
        const int d = tid >> 1, h = tid & 1;
        const int c0 = h ? 13 : 0, c1 = h ? 25 : 13;
        float s = 0.f;
        for (int c = c0; c < c1; ++c) {
            ushort8v v = *(const ushort8v*)&encS[d * 200 + c * 8];
#pragma unroll
            for (int jj = 0; jj < 8; ++jj) s += b2f(v[jj]) * scratch[c * 8 + jj];
        }
        s += __shfl_xor(s, 1, 64);
        float gs = s * ld_f32(&gate_buf[b * 768 + d0 + d]);
        unsigned pk = f2bf(gs);
        unsigned nb = __shfl_down(pk, 2, 64);
        if ((tid & 3) == 0)
            st_u32((unsigned*)(Ab_r + b * 1280 + d0 + d), pk | (nb << 16));
    }
    __syncthreads();
}

// ---------- persistent recurrence kernel (224 blocks: residency margin) ----------
// Roles: g<64:    S1 (att2/gate MFMA, WpreL in LDS) + awe(g) + S3(cols g*4)
//        64..127: awe(g) + awe(192+(g-64)) + S3(cols g*4)
//        128..191: awe(g)
//        192..223: ESET — att1[b] in LDS, e + softmax -> alpha (non-redundant)
// S3: 128 blocks, each computes ALL 32 batch rows x 16 gate-cols (two MFMA chains).
// 4 fence-free barriers/step; cross-block data agent-coherent; big operands in LDS.
__global__ __launch_bounds__(256, 1) void k_recur(
    const ushort_t* __restrict__ att1, const ushort_t* __restrict__ encTb,
    const ushort_t* __restrict__ W_preT, const float* __restrict__ b_da,
    const float* __restrict__ b_fb, const float* __restrict__ w_fa,
    const float* __restrict__ b_fa, const ushort_t* __restrict__ WgT,
    const float* __restrict__ Xih, const float* __restrict__ c0,
    ushort_t* __restrict__ Abuf, float* __restrict__ att2_buf,
    float* __restrict__ gate_buf, float* __restrict__ alpha_buf,
    ushort_t* __restrict__ Hall, unsigned* __restrict__ barflags)
{
    __shared__ __align__(16) char smem[126208];
    float* scratch = (float*)smem;                             // 2048 floats = 8,192 B
    char* R = smem + 8192;                                     // role-specific region

    const int g = (int)blockIdx.x;
    const int tid = (int)threadIdx.x;
    const int lane = tid & 63, wv = tid >> 6;
    const int quad = lane >> 4, c16 = lane & 15;

    const bool isS3 = (g < 128);
    const bool isS1 = (g < 64);
    const bool isE  = (g >= 192);
    const int j0 = g << 2;                                     // S3 cols (g<128)

    ushort_t (*Wl)[1288] = (ushort_t(*)[1288])R;               // S3: 41,216 B
    ushort_t* WpreL = (ushort_t*)(R + 41216);                  // S1: [16][520] = 16,640 B
    ushort_t* enc0  = isS1 ? (ushort_t*)(R + 57856)
                    : (isS3 ? (ushort_t*)(R + 41216) : (ushort_t*)R);  // [96][200] = 38,400 B
    ushort_t* enc1  = (ushort_t*)(R + 79616);                  // blocks 64..127 only
    ushort_t* att1L = (ushort_t*)R;                            // ESET: [197][264] = 104,016 B

    // ---- one-time staging ----
    if (isS3) {                                                // Wl: 16 Wg cols
        int r = tid >> 4, ch = tid & 15;
        int coln = ((r >> 2) << 9) + j0 + (r & 3);
        const ushort_t* src = WgT + (size_t)coln * 1280 + ch * 80;
        ushort_t* dst = &Wl[r][ch * 80];
#pragma unroll
        for (int i = 0; i < 10; ++i)
            *(ushort8v*)(dst + i * 8) = *(const ushort8v*)(src + i * 8);
    }
    if (isS1) {
        const int n0 = g << 4;
#pragma unroll
        for (int i = 0; i < 4; ++i) {
            int c = tid + i * 256;                             // 1024 chunks of 16B
            int r = c >> 6, col8 = (c & 63) * 8;
            *(ushort8v*)&WpreL[r * 520 + col8] = *(const ushort8v*)&W_preT[(size_t)(n0 + r) * 512 + col8];
        }
    }
    if (!isE) {
        const ushort_t* src = encTb + ((size_t)((g >> 3) * 768 + (g & 7) * 96)) * 200;
        for (int i = 0; i < 10; ++i) {
            int c = tid + i * 256;
            if (c < 2400) *(ushort8v*)&enc0[c * 8] = *(const ushort8v*)&src[c * 8];
        }
        if (g >= 64 && g < 128) {
            int task1 = 192 + (g - 64);
            const ushort_t* src1 = encTb + ((size_t)((task1 >> 3) * 768 + (task1 & 7) * 96)) * 200;
            for (int i = 0; i < 10; ++i) {
                int c = tid + i * 256;
                if (c < 2400) *(ushort8v*)&enc1[c * 8] = *(const ushort8v*)&src1[c * 8];
            }
        }
    } else {
        const int eb = g - 192;
        for (int i = 0; i < 25; ++i) {
            int c = tid + i * 256;                             // 6304 chunks of 16B
            if (c < 6304) {
                int p = c >> 5, off = (c & 31) * 8;
                *(ushort8v*)&att1L[p * 264 + off] = *(const ushort8v*)&att1[((size_t)(eb * Pz + p)) * 256 + off];
            }
        }
    }
    float creg = 0.f;
    if (isS3 && tid < 128) creg = c0[(tid >> 2) * HIDz + j0 + (tid & 3)];
    __syncthreads();

    unsigned bt = 0;
    for (int t = 0; t < Tz; ++t) {
        ushort_t* Ab_r = Abuf + (size_t)(t & 1) * 40960;
        ushort_t* Ab_w = Abuf + (size_t)((t + 1) & 1) * 40960;

        // ============ S1: pre-GEMM (att2 + gate) ============
        if (isS1) {
            const int n0 = g << 4;
            frag_cd a0 = (frag_cd){0.f, 0.f, 0.f, 0.f};
            frag_cd a1 = (frag_cd){0.f, 0.f, 0.f, 0.f};
            const ushort_t* Wp = WpreL + (size_t)c16 * 520;
            const ushort_t* Ah = Ab_r + 768;
            const int kbase = wv * 128 + quad * 8;
#pragma unroll
            for (int kk = 0; kk < 4; ++kk) {
                const int kcol = kbase + kk * 32;
                frag_ab bfr = *(const frag_ab*)&Wp[kcol];
                a0 = MFMA16(ldfrag(&Ah[c16 * 1280 + kcol]), bfr, a0);
                a1 = MFMA16(ldfrag(&Ah[(16 + c16) * 1280 + kcol]), bfr, a1);
            }
#pragma unroll
            for (int r = 0; r < 4; ++r) {
                scratch[wv * 512 + (quad * 4 + r) * 16 + c16] = a0[r];
                scratch[wv * 512 + 256 + (quad * 4 + r) * 16 + c16] = a1[r];
            }
            __syncthreads();
#pragma unroll
            for (int h = 0; h < 2; ++h) {
                int idx = tid + h * 256;
                int m = idx >> 4, nl = idx & 15, n = n0 + nl;
                int base = (m >> 4) * 256 + (m & 15) * 16 + nl;
                float v = scratch[base] + scratch[512 + base] +
                          scratch[1024 + base] + scratch[1536 + base];
                if (n < 256) st_f32(&att2_buf[m * 256 + n], v + b_da[n]);
                else st_f32(&gate_buf[m * 768 + n - 256], sigf(v + b_fb[n - 256]));
            }
        }
        gbar(barflags, ++bt, g, tid);

        // ============ S2a: e + softmax -> alpha (ESET only) ============
        if (isE) {
            const int eb = g - 192;
            scratch[tid] = ld_f32(&att2_buf[eb * 256 + tid]);
            scratch[256 + tid] = w_fa[tid];
            __syncthreads();
            float ev = -3.0e38f;
            if (tid < Pz) {
                const ushort_t* ar = att1L + tid * 264;
                float s = 0.f;
#pragma unroll
                for (int j8 = 0; j8 < 256; j8 += 8) {
                    ushort8v v = *(const ushort8v*)&ar[j8];
#pragma unroll
                    for (int jj = 0; jj < 8; ++jj)
                        s += fmaxf(b2f(v[jj]) + scratch[j8 + jj], 0.f) * scratch[256 + j8 + jj];
                }
                ev = s + b_fa[0];
            }
            float mv = ev;
            for (int o = 32; o; o >>= 1) mv = fmaxf(mv, __shfl_down(mv, o, 64));
            if (lane == 0) scratch[512 + wv] = mv;
            __syncthreads();
            const float mx = fmaxf(fmaxf(scratch[512], scratch[513]), fmaxf(scratch[514], scratch[515]));
            float ex = (tid < Pz) ? __expf(ev - mx) : 0.f;
            float sv = ex;
            for (int o = 32; o; o >>= 1) sv += __shfl_down(sv, o, 64);
            if (lane == 0) scratch[516 + wv] = sv;
            __syncthreads();
            const float inv = 1.f / (scratch[516] + scratch[517] + scratch[518] + scratch[519]);
            if (tid < 200) st_f32(&alpha_buf[eb * 200 + tid], ex * inv);
        }
        gbar(barflags, ++bt, g, tid);

        // ============ S2b: awe + gate -> gawe (bf16 into Ab_r) ============
        if (!isE) {
            do_awe(g, enc0, scratch, gate_buf, alpha_buf, Ab_r, tid);
            if (g >= 64 && g < 128)
                do_awe(192 + (g - 64), enc1, scratch, gate_buf, alpha_buf, Ab_r, tid);
        }
        gbar(barflags, ++bt, g, tid);

        // ============ S3: gates GEMM (32 rows x 16 cols) + LSTM ============
        if (isS3) {
            frag_cd p0 = (frag_cd){0.f, 0.f, 0.f, 0.f};
            frag_cd p1 = (frag_cd){0.f, 0.f, 0.f, 0.f};
            const ushort_t* Ar0 = Ab_r + (size_t)c16 * 1280 + wv * 320 + quad * 8;
            const ushort_t* Ar1 = Ar0 + 16 * 1280;
            const ushort_t* Wr = &Wl[c16][wv * 320 + quad * 8];
#pragma unroll
            for (int ks = 0; ks < 10; ++ks) {
                frag_ab bfr = *(const frag_ab*)(Wr + ks * 32);
                p0 = MFMA16(ldfrag(Ar0 + ks * 32), bfr, p0);
                p1 = MFMA16(ldfrag(Ar1 + ks * 32), bfr, p1);
            }
#pragma unroll
            for (int r = 0; r < 4; ++r) {
                scratch[wv * 512 + (quad * 4 + r) * 16 + c16] = p0[r];
                scratch[wv * 512 + 256 + (quad * 4 + r) * 16 + c16] = p1[r];
            }
            __syncthreads();
            float s0, s1;
            {
                const int mr = tid >> 4, col = tid & 15;
                const int base = mr * 16 + col;
                const int xcol = ((col >> 2) << 9) + j0 + (col & 3);
                s0 = scratch[base] + scratch[512 + base] + scratch[1024 + base] + scratch[1536 + base]
                   + Xih[(size_t)t * 65536 + mr * 2048 + xcol];
                s1 = scratch[256 + base] + scratch[768 + base] + scratch[1280 + base] + scratch[1792 + base]
                   + Xih[(size_t)t * 65536 + (16 + mr) * 2048 + xcol];
            }
            __syncthreads();
            scratch[tid] = s0;
            scratch[256 + tid] = s1;
            __syncthreads();
            if (tid < 128) {
                const int bl = tid >> 2, jj = tid & 3, j = j0 + jj;
                const float iv = scratch[bl * 16 + jj], fv = scratch[bl * 16 + 4 + jj];
                const float gv = scratch[bl * 16 + 8 + jj], ov = scratch[bl * 16 + 12 + jj];
                const float cn = sigf(fv) * creg + sigf(iv) * tanhfast(gv);
                creg = cn;
                const float hn = sigf(ov) * tanhfast(cn);
                const ushort_t hb = f2bf(hn);
                Hall[((size_t)t * 32 + bl) * HIDz + j] = hb;
                unsigned pk = hb;
                unsigned nb = __shfl_down(pk, 1, 64);
                if ((tid & 1) == 0)
                    st_u32((unsigned*)(Ab_w + bl * 1280 + 768 + j), pk | (nb << 16));
            }
        }
        if (t < Tz - 1) gbar(barflags, ++bt, g, tid);
    }
}

// ---------- launcher ----------
extern "C" void kernel_launch(void* const* d_in, const int* in_sizes, int n_in,
                              void* d_out, int out_size, void* d_ws, size_t ws_size,
                              hipStream_t stream) {
    const float* enc   = (const float*)d_in[0];
    const int*   caps  = (const int*)d_in[1];
    const float* emb   = (const float*)d_in[2];
    const float* W_ea  = (const float*)d_in[3];
    const float* b_ea  = (const float*)d_in[4];
    const float* W_da  = (const float*)d_in[5];
    const float* b_da  = (const float*)d_in[6];
    const float* w_fa  = (const float*)d_in[7];
    const float* b_fa  = (const float*)d_in[8];
    const float* W_inh = (const float*)d_in[9];
    const float* b_inh = (const float*)d_in[10];
    const float* W_inc = (const float*)d_in[11];
    const float* b_inc = (const float*)d_in[12];
    const float* W_fb  = (const float*)d_in[13];
    const float* b_fb  = (const float*)d_in[14];
    const float* W_ih  = (const float*)d_in[15];
    const float* b_ih  = (const float*)d_in[16];
    const float* W_hh  = (const float*)d_in[17];
    const float* b_hh  = (const float*)d_in[18];
    const float* W_out = (const float*)d_in[19];
    const float* b_out = (const float*)d_in[20];

    char* ws = (char*)d_ws;
    ushort_t* att1     = (ushort_t*)(ws + 0);            // 6304x256 bf16     -> 3,227,648
    ushort_t* Xemb     = (ushort_t*)(ws + 3227648);      // 1280x512 bf16     -> 4,538,368
    ushort_t* encB     = (ushort_t*)(ws + 4538368);      // 6304x768 bf16     -> 14,221,312
    float*    Xih      = (float*)(ws + 14221312);        // 40x32x2048 fp32   -> 24,707,072
    float*    meanE    = (float*)(ws + 24707072);        // 32x768 fp32       -> 24,805,376
    float*    c_cur    = (float*)(ws + 24805376);        // 32x512 fp32       -> 24,870,912
    ushort_t* Abuf     = (ushort_t*)(ws + 24870912);     // 2 x 32x1280 bf16  -> 25,034,752
    float*    att2_buf = (float*)(ws + 25034752);        // 32x256 fp32       -> 25,067,520
    float*    gate_buf = (float*)(ws + 25067520);        // 32x768 fp32       -> 25,165,824
    float*    alpha_buf= (float*)(ws + 25165824);        // 32x200 fp32       -> 25,191,424
    ushort_t* Hall     = (ushort_t*)(ws + 25191424);     // 1280x512 bf16     -> 26,502,144
    ushort_t* WgT      = (ushort_t*)(ws + 26502144);     // 2048x1280 bf16    -> 31,745,024
    ushort_t* W_preT   = (ushort_t*)(ws + 31745024);     // 1024x512 bf16     -> 32,793,600
    ushort_t* W_eaT    = (ushort_t*)(ws + 32793600);     // 256x768 bf16      -> 33,186,816
    ushort_t* W_ihxT   = (ushort_t*)(ws + 33186816);     // 2048x512 bf16     -> 35,283,968
    ushort_t* W_outT   = (ushort_t*)(ws + 35283968);     // 32000x512 bf16    -> 68,051,968
    ushort_t* encTb    = (ushort_t*)(ws + 68051968);     // 32x768x200 bf16   -> 77,882,368
    unsigned* barflags = (unsigned*)(ws + 77882368);     // 224 x 128 B = 28,672 B

    // precompute (order-independent, single stream)
    k_binit<<<1, 256, 0, stream>>>(barflags);
    k_conv<<<2364, 256, 0, stream>>>(enc, encB);         // 32*197*768 = 2364*2048
    k_mean<<<96, 256, 0, stream>>>(enc, meanE);
    k_h0c0<<<128, 256, 0, stream>>>(meanE, W_inh, b_inh, W_inc, b_inc, c_cur, Abuf);
    k_gather<<<1280, 128, 0, stream>>>(caps, emb, Xemb);
    k_encTb<<<dim3(24, 7, 32), 256, 0, stream>>>(enc, encTb);
    k_transpose<<<dim3(8, 24), 256, 0, stream>>>(W_ea, 768, 256, W_eaT, 768, 0);
    k_transpose<<<dim3(64, 16), 256, 0, stream>>>(W_ih, 512, 2048, W_ihxT, 512, 0);
    k_transpose<<<dim3(64, 24), 256, 0, stream>>>(W_ih + 512 * 2048, 768, 2048, WgT, 1280, 0);
    k_transpose<<<dim3(64, 16), 256, 0, stream>>>(W_hh, 512, 2048, WgT, 1280, 768);
    k_transpose<<<dim3(8, 16), 256, 0, stream>>>(W_da, 512, 256, W_preT, 512, 0);
    k_transpose<<<dim3(24, 16), 256, 0, stream>>>(W_fb, 512, 768, W_preT + 256 * 512, 512, 0);
    k_transpose<<<dim3(1000, 16), 256, 0, stream>>>(W_out, 512, 32000, W_outT, 512, 0);

    // att1 = enc @ W_ea + b_ea   (bf16 out, row-major [b*197+p][256])
    k_gemm<1><<<dim3(2, 50), 256, 0, stream>>>(encB, 768, 6304, W_eaT, 768, b_ea, nullptr, att1, 256);
    // Xih = Xemb @ W_ih[:512] + b_ih + b_hh  (fp32 out)
    k_gemm<0><<<dim3(16, 10), 256, 0, stream>>>(Xemb, 512, 1280, W_ihxT, 512, b_ih, b_hh, Xih, 2048);

    // full 40-step recurrence: one persistent kernel (224 blocks), 4 fence-free barriers/step
    hipLaunchKernelGGL(k_recur, dim3(NBLK), dim3(256), 0, stream,
                       att1, encTb, W_preT, b_da, b_fb, w_fa, b_fa, WgT, Xih,
                       c_cur, Abuf, att2_buf, gate_buf, alpha_buf, Hall, barflags);

    // preds = Hall @ W_out + b_out -> d_out (B,T,V) fp32
    k_gemm<2><<<dim3(250, 10), 256, 0, stream>>>(Hall, 512, 1280, W_outT, 512, b_out, nullptr, d_out, VOCz);
}